// Round 11
// baseline (2853.300 us; speedup 1.0000x reference)
//
#include <hip/hip_runtime.h>
#include <hip/hip_bf16.h>

#define B_ 2
#define T_ 512
#define D_ 512
#define H_ 8
#define L_ 6
#define F_ 2048
#define V_ 32000
#define BT_ (B_ * T_)
#define HD_ (H_ * D_)
#define BH_ (B_ * H_)

typedef __attribute__((ext_vector_type(8))) short short8;
typedef __attribute__((ext_vector_type(4))) short short4v;
typedef __attribute__((ext_vector_type(4))) float f32x4;

__device__ __forceinline__ short f2b(float f) {
  __hip_bfloat16 h = __float2bfloat16(f);
  short u; __builtin_memcpy(&u, &h, 2); return u;
}
__device__ __forceinline__ void store_c(float* p, float v) { *p = v; }
__device__ __forceinline__ void store_c(short* p, float v) { *p = f2b(v); }

// ---------------- embedding * sqrt(D) + sinusoidal PE (f32 + bf16 copies) ----------------
__global__ __launch_bounds__(256) void embed_kernel(
    const int* __restrict__ tok, const float* __restrict__ emb,
    float* __restrict__ out, short* __restrict__ out16)
{
  const int row = blockIdx.x;            // b*T + t
  const int t = row & (T_ - 1);
  const int token = tok[row];
  const float* e = emb + (size_t)token * D_;
  float* o = out + (size_t)row * D_;
  short* o16 = out16 + (size_t)row * D_;
  const float scale = sqrtf((float)D_);
  const float nl = -logf(10000.0f);
  for (int d = threadIdx.x; d < D_; d += 256) {
    int i = d >> 1;
    float wl = expf(nl * (2.0f * (float)i) / (float)D_);
    float ang = (float)t * wl;
    float pe = (d & 1) ? cosf(ang) : sinf(ang);
    float v = e[d] * scale + pe;
    o[d] = v; o16[d] = f2b(v);
  }
}

// ---------------- generic MFMA GEMM (r6 structure: single-buffer + reg prefetch) --------
// A: bf16 [.,K] k-contig. B: BTM ? bf16 [N][K] k-contig : f32 [K][N].
// BM in {64,128}, BN=128. z = batch(nh) x ksplit. Optional transposed bf16
// store for hh==trans_hh; fused relu; causal_skip drops upper-triangle blocks.
template<bool BTM, typename OutT, int BM>
__global__ __launch_bounds__(256, 3) void mfma_gemm(
    const short* __restrict__ A, long lda, long a_hi, long a_lo,
    const void* __restrict__ Bv, long ldb, long b_hi, long b_lo,
    OutT* __restrict__ C, long ldc, long c_hi, long c_lo, long pstride,
    short* __restrict__ Ct, int trans_hh, int relu, int causal_skip,
    int K, int nh, int ksplit, float scale,
    const float* __restrict__ bias, long bias_stride)
{
  constexpr int SA = BM + 1;
  constexpr int AU = BM / 32;
  constexpr int WRN = (BM == 128) ? 2 : 1;
  constexpr int WN  = (BM == 128) ? 64 : 32;
  constexpr int NR  = WN / 16;
  __shared__ short8 As8[8 * SA];
  __shared__ short8 Bs8[8 * 129];
  const int tid = threadIdx.x;
  const int bh = blockIdx.z / ksplit;
  const int kz = blockIdx.z - bh * ksplit;
  const int bb = bh / nh, hh = bh - bb * nh;
  const short* Ab = A + (long)bb * a_hi + (long)hh * a_lo;
  const short* Bbs = (const short*)Bv + (long)bb * b_hi + (long)hh * b_lo;
  const float* Bbf = (const float*)Bv + (long)bb * b_hi + (long)hh * b_lo;
  OutT* Cb = C + (long)bb * c_hi + (long)hh * c_lo + (long)kz * pstride;

  const int gx = gridDim.x, gy = gridDim.y;
  const int nwg = gx * gy;
  int lin = blockIdx.y * gx + blockIdx.x;
  {
    const int xcd = lin & 7, idx = lin >> 3;
    const int q = nwg >> 3, r = nwg & 7;
    lin = (xcd < r ? xcd * (q + 1) : r * (q + 1) + (xcd - r) * q) + idx;
  }
  const int bn = (lin / gy) * 128;
  const int bm = (lin % gy) * BM;
  if (causal_skip && bn > bm + BM - 1) return;   // upper triangle: S never read

  const int klen = K / ksplit, kbase = kz * klen;
  const int lane = tid & 63, wid = tid >> 6;
  const int wr = (WRN == 2) ? (wid >> 1) : 0;
  const int wc = (WRN == 2) ? (wid & 1) : wid;
  const int lg = lane >> 4, r16 = lane & 15;

  int arow[AU], acol[AU];
#pragma unroll
  for (int u = 0; u < AU; ++u) { int o = u * 256 + tid; arow[u] = o >> 3; acol[u] = o & 7; }
  int brow[4], bcol[4];
#pragma unroll
  for (int u = 0; u < 4; ++u) { int o = u * 256 + tid; brow[u] = o >> 3; bcol[u] = o & 7; }
  const int ncol = tid & 127, nsh = tid >> 7;

  short8 pa[AU];
  short8 pbt[4];
  float  pbn[4][8];

  auto load = [&](int k0) {
#pragma unroll
    for (int u = 0; u < AU; ++u)
      pa[u] = *(const short8*)(Ab + (long)(bm + arow[u]) * lda + (k0 + acol[u] * 8));
    if constexpr (BTM) {
#pragma unroll
      for (int u = 0; u < 4; ++u)
        pbt[u] = *(const short8*)(Bbs + (long)(bn + brow[u]) * ldb + (k0 + bcol[u] * 8));
    } else {
      const float* s = Bbf + (long)(k0 + nsh * 32) * ldb + (bn + ncol);
#pragma unroll
      for (int i = 0; i < 4; ++i)
#pragma unroll
        for (int j = 0; j < 8; ++j)
          pbn[i][j] = s[(long)(i * 8 + j) * ldb];
    }
  };
  auto stage = [&]() {
#pragma unroll
    for (int u = 0; u < AU; ++u) As8[acol[u] * SA + arow[u]] = pa[u];
    if constexpr (BTM) {
#pragma unroll
      for (int u = 0; u < 4; ++u) Bs8[bcol[u] * 129 + brow[u]] = pbt[u];
    } else {
#pragma unroll
      for (int i = 0; i < 4; ++i) {
        short8 v;
#pragma unroll
        for (int j = 0; j < 8; ++j) v[j] = f2b(pbn[i][j]);
        Bs8[(nsh * 4 + i) * 129 + ncol] = v;
      }
    }
  };

  f32x4 acc[4][NR] = {};
  auto domfma = [&]() {
#pragma unroll
    for (int kb = 0; kb < 2; ++kb) {
      const int cha = (kb * 4 + lg) * SA;
      const int chb = (kb * 4 + lg) * 129;
      short8 a0 = As8[cha + wr * 64 +  0 + r16];
      short8 a1 = As8[cha + wr * 64 + 16 + r16];
      short8 a2 = As8[cha + wr * 64 + 32 + r16];
      short8 a3 = As8[cha + wr * 64 + 48 + r16];
#pragma unroll
      for (int n = 0; n < NR; ++n) {
        short8 bfr = Bs8[chb + wc * WN + n * 16 + r16];
        acc[0][n] = __builtin_amdgcn_mfma_f32_16x16x32_bf16(a0, bfr, acc[0][n], 0, 0, 0);
        acc[1][n] = __builtin_amdgcn_mfma_f32_16x16x32_bf16(a1, bfr, acc[1][n], 0, 0, 0);
        acc[2][n] = __builtin_amdgcn_mfma_f32_16x16x32_bf16(a2, bfr, acc[2][n], 0, 0, 0);
        acc[3][n] = __builtin_amdgcn_mfma_f32_16x16x32_bf16(a3, bfr, acc[3][n], 0, 0, 0);
      }
    }
  };

  load(kbase);
  stage();
  __syncthreads();
  const int nsteps = klen >> 6;
  for (int t = 0; t < nsteps; ++t) {
    const bool more = (t + 1 < nsteps);
    if (more) load(kbase + (t + 1) * 64);
    domfma();
    if (more) { __syncthreads(); stage(); __syncthreads(); }
  }

  const float* bp = bias ? bias + (long)hh * bias_stride : nullptr;
  if (hh == trans_hh) {
#pragma unroll
    for (int m = 0; m < 4; ++m)
#pragma unroll
      for (int n = 0; n < NR; ++n) {
        const int col = bn + wc * WN + n * 16 + r16;
        const float badd = bp ? bp[col] : 0.0f;
        short4v sv;
#pragma unroll
        for (int rr = 0; rr < 4; ++rr) sv[rr] = f2b(acc[m][n][rr] * scale + badd);
        *(short4v*)(Ct + (long)col * BT_ + (bm + wr * 64 + m * 16 + lg * 4)) = sv;
      }
  } else {
#pragma unroll
    for (int m = 0; m < 4; ++m)
#pragma unroll
      for (int rr = 0; rr < 4; ++rr) {
        const int row = bm + wr * 64 + m * 16 + lg * 4 + rr;
        OutT* crow = Cb + (long)row * ldc + bn + wc * WN + r16;
#pragma unroll
        for (int n = 0; n < NR; ++n) {
          float v = acc[m][n][rr] * scale;
          if (bp) v += bp[bn + wc * WN + n * 16 + r16];
          if (relu) v = fmaxf(v, 0.0f);
          store_c(&crow[n * 16], v);
        }
      }
  }
}

// ---------------- fused softmax + PV: O = softmax_row(S) * V ----------------
// r6 GEMM structure, BM=64, BN=128, 4 waves. A = S (f32 scores, scaled), staged
// as bf16 exp(s - rowmax) on the fly; epilogue scales by 1/rowsum.
// Prepass computes rowmax/rowsum (4 threads/row, shfl). Causal: k-steps beyond
// the diagonal are skipped entirely; diagonal step masks col > qrow.
__global__ __launch_bounds__(256, 3) void smpv_kernel(
    const float* __restrict__ S, const short* __restrict__ Vt,
    short* __restrict__ O, int causal)
{
  __shared__ short8 As8[8 * 65];
  __shared__ short8 Bs8[8 * 129];
  __shared__ float mrow[64], linv[64];

  const int tid = threadIdx.x;
  const int bh = blockIdx.z;
  const int b = bh >> 3, hh = bh & 7;
  const int bm = blockIdx.y * 64;
  const int bn = blockIdx.x * 128;
  const int lane = tid & 63, w4 = tid >> 6;
  const int lg = lane >> 4, r16 = lane & 15;

  const float* Sb = S + (long)bh * T_ * T_;
  const short* Vb = Vt + ((long)hh * D_ + bn) * BT_ + (long)b * T_;

  // ---- prepass: per-row max and 1/sum over valid cols ----
  {
    const int row = tid >> 2, sub = tid & 3;
    const int qrow = bm + row;
    const int ncols = causal ? (qrow + 1) : T_;
    const float* sp = Sb + (long)qrow * T_;
    float mx = -3.0e38f;
    for (int i = 0; i < 32; ++i) {
      const int c0 = (sub + i * 4) * 4;
      if (c0 < ncols) {
        float4 v = *(const float4*)(sp + c0);
        mx = fmaxf(mx, v.x);
        if (c0 + 1 < ncols) mx = fmaxf(mx, v.y);
        if (c0 + 2 < ncols) mx = fmaxf(mx, v.z);
        if (c0 + 3 < ncols) mx = fmaxf(mx, v.w);
      }
    }
    mx = fmaxf(mx, __shfl_xor(mx, 1));
    mx = fmaxf(mx, __shfl_xor(mx, 2));
    float sm = 0.0f;
    for (int i = 0; i < 32; ++i) {
      const int c0 = (sub + i * 4) * 4;
      if (c0 < ncols) {
        float4 v = *(const float4*)(sp + c0);
        sm += expf(v.x - mx);
        if (c0 + 1 < ncols) sm += expf(v.y - mx);
        if (c0 + 2 < ncols) sm += expf(v.z - mx);
        if (c0 + 3 < ncols) sm += expf(v.w - mx);
      }
    }
    sm += __shfl_xor(sm, 1);
    sm += __shfl_xor(sm, 2);
    if (sub == 0) { mrow[row] = mx; linv[row] = 1.0f / sm; }
  }
  __syncthreads();

  int arow[2], acol[2];
#pragma unroll
  for (int u = 0; u < 2; ++u) { int o = u * 256 + tid; arow[u] = o >> 3; acol[u] = o & 7; }
  int brow[4], bcol[4];
#pragma unroll
  for (int u = 0; u < 4; ++u) { int o = u * 256 + tid; brow[u] = o >> 3; bcol[u] = o & 7; }

  float4 pa[2][2];
  short8 pbt[4];

  auto load = [&](int k0) {
#pragma unroll
    for (int u = 0; u < 2; ++u) {
      const float* s = Sb + (long)(bm + arow[u]) * T_ + (k0 + acol[u] * 8);
      pa[u][0] = *(const float4*)(s);
      pa[u][1] = *(const float4*)(s + 4);
    }
#pragma unroll
    for (int u = 0; u < 4; ++u)
      pbt[u] = *(const short8*)(Vb + (long)brow[u] * BT_ + (k0 + bcol[u] * 8));
  };
  auto stage = [&](int k0, bool mask) {
#pragma unroll
    for (int u = 0; u < 2; ++u) {
      const int row = arow[u];
      const int qrow = bm + row;
      const float m = mrow[row];
      const float vals[8] = {pa[u][0].x, pa[u][0].y, pa[u][0].z, pa[u][0].w,
                             pa[u][1].x, pa[u][1].y, pa[u][1].z, pa[u][1].w};
      short8 v;
#pragma unroll
      for (int j = 0; j < 8; ++j) {
        const bool valid = !mask || (k0 + acol[u] * 8 + j <= qrow);
        v[j] = f2b(valid ? expf(vals[j] - m) : 0.0f);
      }
      As8[acol[u] * 65 + row] = v;
    }
#pragma unroll
    for (int u = 0; u < 4; ++u) Bs8[bcol[u] * 129 + brow[u]] = pbt[u];
  };

  f32x4 acc[4][2] = {};
  auto domfma = [&]() {
#pragma unroll
    for (int kb = 0; kb < 2; ++kb) {
      const int cha = (kb * 4 + lg) * 65;
      const int chb = (kb * 4 + lg) * 129;
      short8 a0 = As8[cha +  0 + r16];
      short8 a1 = As8[cha + 16 + r16];
      short8 a2 = As8[cha + 32 + r16];
      short8 a3 = As8[cha + 48 + r16];
#pragma unroll
      for (int n = 0; n < 2; ++n) {
        short8 bfr = Bs8[chb + w4 * 32 + n * 16 + r16];
        acc[0][n] = __builtin_amdgcn_mfma_f32_16x16x32_bf16(a0, bfr, acc[0][n], 0, 0, 0);
        acc[1][n] = __builtin_amdgcn_mfma_f32_16x16x32_bf16(a1, bfr, acc[1][n], 0, 0, 0);
        acc[2][n] = __builtin_amdgcn_mfma_f32_16x16x32_bf16(a2, bfr, acc[2][n], 0, 0, 0);
        acc[3][n] = __builtin_amdgcn_mfma_f32_16x16x32_bf16(a3, bfr, acc[3][n], 0, 0, 0);
      }
    }
  };

  const int nsteps = causal ? ((bm >> 6) + 1) : (T_ >> 6);
  load(0);
  stage(0, causal && (0 >= bm));
  __syncthreads();
  for (int t = 0; t < nsteps; ++t) {
    const bool more = (t + 1 < nsteps);
    if (more) load((t + 1) * 64);
    domfma();
    if (more) {
      __syncthreads();
      stage((t + 1) * 64, causal && ((t + 1) * 64 >= bm));
      __syncthreads();
    }
  }

  short* Ob = O + ((long)b * T_ + bm) * HD_ + hh * D_ + bn;
#pragma unroll
  for (int m = 0; m < 4; ++m)
#pragma unroll
    for (int rr = 0; rr < 4; ++rr) {
      const int row = m * 16 + lg * 4 + rr;
      const float il = linv[row];
#pragma unroll
      for (int n = 0; n < 2; ++n)
        Ob[(long)row * HD_ + w4 * 32 + n * 16 + r16] = f2b(acc[m][n][rr] * il);
    }
}

// ---- fused: x = resid + bias + sum_z partial; resid(f32) = LN(x)*g+b; + bf16 copy ----
__global__ __launch_bounds__(256) void reduce_ln_kernel(
    const float* __restrict__ P, long pstride, int ks,
    const float* __restrict__ bias, float* __restrict__ hbuf, short* __restrict__ h16,
    const float* __restrict__ gam, const float* __restrict__ bet)
{
  __shared__ float red[256];
  const int row = blockIdx.x, tid = threadIdx.x;
  const long base = (long)row * D_;
  float s0 = hbuf[base + tid] + bias[tid];
  float s1 = hbuf[base + tid + 256] + bias[tid + 256];
  for (int z = 0; z < ks; ++z) {
    s0 += P[(long)z * pstride + base + tid];
    s1 += P[(long)z * pstride + base + tid + 256];
  }
  red[tid] = s0 + s1; __syncthreads();
  for (int o = 128; o > 0; o >>= 1) { if (tid < o) red[tid] += red[tid + o]; __syncthreads(); }
  const float mean = red[0] * (1.0f / D_); __syncthreads();
  const float d0 = s0 - mean, d1 = s1 - mean;
  red[tid] = d0 * d0 + d1 * d1; __syncthreads();
  for (int o = 128; o > 0; o >>= 1) { if (tid < o) red[tid] += red[tid + o]; __syncthreads(); }
  const float inv = rsqrtf(red[0] * (1.0f / D_) + 1e-6f);
  const float v0 = d0 * inv * gam[tid] + bet[tid];
  const float v1 = d1 * inv * gam[tid + 256] + bet[tid + 256];
  hbuf[base + tid] = v0;       h16[base + tid] = f2b(v0);
  hbuf[base + tid + 256] = v1; h16[base + tid + 256] = f2b(v1);
}

extern "C" void kernel_launch(void* const* d_in, const int* in_sizes, int n_in,
                              void* d_out, int out_size, void* d_ws, size_t ws_size,
                              hipStream_t stream)
{
  const int*   x         = (const int*)d_in[0];
  const int*   y         = (const int*)d_in[1];
  const float* enc_emb   = (const float*)d_in[2];
  const float* dec_emb   = (const float*)d_in[3];
  const float* enc_qkv_w = (const float*)d_in[4];
  const float* enc_qkv_b = (const float*)d_in[5];
  const float* enc_out_w = (const float*)d_in[6];
  const float* enc_out_b = (const float*)d_in[7];
  const float* enc_ln1_g = (const float*)d_in[8];
  const float* enc_ln1_b = (const float*)d_in[9];
  const float* enc_ff_w1 = (const float*)d_in[10];
  const float* enc_ff_b1 = (const float*)d_in[11];
  const float* enc_ff_w2 = (const float*)d_in[12];
  const float* enc_ff_b2 = (const float*)d_in[13];
  const float* enc_ln2_g = (const float*)d_in[14];
  const float* enc_ln2_b = (const float*)d_in[15];
  const float* dec_sa_qkv_w = (const float*)d_in[16];
  const float* dec_sa_qkv_b = (const float*)d_in[17];
  const float* dec_sa_out_w = (const float*)d_in[18];
  const float* dec_sa_out_b = (const float*)d_in[19];
  const float* dec_ln1_g = (const float*)d_in[20];
  const float* dec_ln1_b = (const float*)d_in[21];
  const float* dec_ca_qkv_w = (const float*)d_in[22];
  const float* dec_ca_qkv_b = (const float*)d_in[23];
  const float* dec_ca_out_w = (const float*)d_in[24];
  const float* dec_ca_out_b = (const float*)d_in[25];
  const float* dec_ln2_g = (const float*)d_in[26];
  const float* dec_ln2_b = (const float*)d_in[27];
  const float* dec_ff_w1 = (const float*)d_in[28];
  const float* dec_ff_b1 = (const float*)d_in[29];
  const float* dec_ff_w2 = (const float*)d_in[30];
  const float* dec_ff_b2 = (const float*)d_in[31];
  const float* dec_ln3_g = (const float*)d_in[32];
  const float* dec_ln3_b = (const float*)d_in[33];
  const float* head_w    = (const float*)d_in[34];
  const float* head_b    = (const float*)d_in[35];
  float* out = (float*)d_out;

  // ---- workspace carve-up ----
  char* wsb = (char*)d_ws;
  size_t off = 0;
  auto carve = [&](size_t bytes) { char* p = wsb + off; off += (bytes + 255) & ~255ull; return p; };
  float* h    = (float*)carve((size_t)BT_ * D_ * 4);
  float* dd   = (float*)carve((size_t)BT_ * D_ * 4);
  short* hb16 = (short*)carve((size_t)BT_ * D_ * 2);
  short* db16 = (short*)carve((size_t)BT_ * D_ * 2);
  short* Qb   = (short*)carve((size_t)BT_ * HD_ * 2);
  short* Kb   = (short*)carve((size_t)BT_ * HD_ * 2);
  short* Vt   = (short*)carve((size_t)HD_ * BT_ * 2);
  float* Sb   = (float*)carve((size_t)BH_ * T_ * T_ * 4);  // S + split-K partials
  short* Ob   = Qb;   // Q dead after QK^T
  short* mid  = Qb;   // attn buffers dead during FFN
  (void)ws_size;

  dim3 blk(256);
  const long TT  = (long)T_ * T_;
  const long THD = (long)T_ * HD_;
  const long WQKV = (long)D_ * HD_;

  auto gemm = [&](bool bt, bool of32, bool bm64, int relu, int cskip,
                  const short* A, long lda, long a_hi, long a_lo,
                  const void* Bp, long ldb, long b_hi, long b_lo,
                  void* Cp, long ldc, long c_hi, long c_lo, long pstride,
                  short* Ct, int trans_hh,
                  int M, int N, int K, int batch, int nh, int ksplit,
                  float scale, const float* bias, long bstride) {
    dim3 grd(N / 128, M / (bm64 ? 64 : 128), batch * ksplit);
    if (bm64) {
      if (bt) {
        if (of32) mfma_gemm<true , float, 64><<<grd, blk, 0, stream>>>(A, lda, a_hi, a_lo, Bp, ldb, b_hi, b_lo,
            (float*)Cp, ldc, c_hi, c_lo, pstride, Ct, trans_hh, relu, cskip, K, nh, ksplit, scale, bias, bstride);
        else      mfma_gemm<true , short, 64><<<grd, blk, 0, stream>>>(A, lda, a_hi, a_lo, Bp, ldb, b_hi, b_lo,
            (short*)Cp, ldc, c_hi, c_lo, pstride, Ct, trans_hh, relu, cskip, K, nh, ksplit, scale, bias, bstride);
      } else {
        if (of32) mfma_gemm<false, float, 64><<<grd, blk, 0, stream>>>(A, lda, a_hi, a_lo, Bp, ldb, b_hi, b_lo,
            (float*)Cp, ldc, c_hi, c_lo, pstride, Ct, trans_hh, relu, cskip, K, nh, ksplit, scale, bias, bstride);
        else      mfma_gemm<false, short, 64><<<grd, blk, 0, stream>>>(A, lda, a_hi, a_lo, Bp, ldb, b_hi, b_lo,
            (short*)Cp, ldc, c_hi, c_lo, pstride, Ct, trans_hh, relu, cskip, K, nh, ksplit, scale, bias, bstride);
      }
    } else {
      if (of32) mfma_gemm<false, float, 128><<<grd, blk, 0, stream>>>(A, lda, a_hi, a_lo, Bp, ldb, b_hi, b_lo,
          (float*)Cp, ldc, c_hi, c_lo, pstride, Ct, trans_hh, relu, cskip, K, nh, ksplit, scale, bias, bstride);
      else      mfma_gemm<false, short, 128><<<grd, blk, 0, stream>>>(A, lda, a_hi, a_lo, Bp, ldb, b_hi, b_lo,
          (short*)Cp, ldc, c_hi, c_lo, pstride, Ct, trans_hh, relu, cskip, K, nh, ksplit, scale, bias, bstride);
    }
  };

  auto attention = [&](const short* qsrc, const short* kvsrc, bool self,
                       const float* qkvw, const float* qkvb,
                       const float* ow, const float* ob,
                       float* resid, short* resid16, int causal,
                       const float* lng, const float* lnb) {
    if (self) {
      // fused Q,K,V (z=3); hh=0->Qb, hh=1->Kb (via c_lo), hh=2 -> transposed Vt
      gemm(false, false, true, 0, 0, qsrc, D_, 0, 0, qkvw, HD_, 0, WQKV,
           Qb, HD_, 0, (long)(Kb - Qb), 0, Vt, 2,
           BT_, HD_, D_, 3, 3, 1, 1.0f, qkvb, HD_);
    } else {
      gemm(false, false, true, 0, 0, qsrc, D_, 0, 0, qkvw, HD_, 0, 0,
           Qb, HD_, 0, 0, 0, nullptr, -1,
           BT_, HD_, D_, 1, 1, 1, 1.0f, qkvb, 0);
      gemm(false, false, true, 0, 0, kvsrc, D_, 0, 0, qkvw + WQKV, HD_, 0, WQKV,
           Kb, HD_, 0, 0, 0, Vt, 1,
           BT_, HD_, D_, 2, 2, 1, 1.0f, qkvb + HD_, HD_);
    }
    // S = Q K^T / sqrt(D); causal drops upper-triangle blocks
    gemm(true, true, true, 0, causal, Qb, HD_, THD, D_, Kb, HD_, THD, D_,
         Sb, T_, (long)H_ * TT, TT, 0, nullptr, -1,
         T_, T_, D_, BH_, H_, 1, 0.044194173824159216f, nullptr, 0);
    // fused softmax + PV
    smpv_kernel<<<dim3(D_ / 128, T_ / 64, BH_), blk, 0, stream>>>(Sb, Vt, Ob, causal);
    // out-projection split-K=4 -> f32 partials in Sb; fused reduce+resid+LN
    gemm(false, true, true, 0, 0, Ob, HD_, 0, 0, ow, D_, 0, 0,
         Sb, D_, 0, 0, (long)BT_ * D_, nullptr, -1,
         BT_, D_, HD_, 1, 1, 4, 1.0f, nullptr, 0);
    reduce_ln_kernel<<<dim3(BT_), blk, 0, stream>>>(
        Sb, (long)BT_ * D_, 4, ob, resid, resid16, lng, lnb);
  };

  auto ffn = [&](float* resid, short* resid16,
                 const float* w1, const float* b1,
                 const float* w2, const float* b2,
                 const float* lng, const float* lnb) {
    // FF1: fused bias+relu epilogue -> bf16 mid (BM=64, grid 256, no split-K)
    gemm(false, false, true, 1, 0, resid16, D_, 0, 0, w1, F_, 0, 0,
         mid, F_, 0, 0, 0, nullptr, -1,
         BT_, F_, D_, 1, 1, 1, 1.0f, b1, 0);
    // FF2: split-K=4 -> f32 partials; fused reduce+resid+LN
    gemm(false, true, true, 0, 0, mid, F_, 0, 0, w2, D_, 0, 0,
         Sb, D_, 0, 0, (long)BT_ * D_, nullptr, -1,
         BT_, D_, F_, 1, 1, 4, 1.0f, nullptr, 0);
    reduce_ln_kernel<<<dim3(BT_), blk, 0, stream>>>(
        Sb, (long)BT_ * D_, 4, b2, resid, resid16, lng, lnb);
  };

  // ---------------- encoder ----------------
  embed_kernel<<<dim3(BT_), blk, 0, stream>>>(x, enc_emb, h, hb16);
  for (int i = 0; i < L_; ++i) {
    attention(hb16, hb16, true,
              enc_qkv_w + (size_t)i * 3 * WQKV, enc_qkv_b + (size_t)i * 3 * HD_,
              enc_out_w + (size_t)i * HD_ * D_, enc_out_b + (size_t)i * D_,
              h, hb16, 0, enc_ln1_g + (size_t)i * D_, enc_ln1_b + (size_t)i * D_);
    ffn(h, hb16, enc_ff_w1 + (size_t)i * D_ * F_, enc_ff_b1 + (size_t)i * F_,
        enc_ff_w2 + (size_t)i * F_ * D_, enc_ff_b2 + (size_t)i * D_,
        enc_ln2_g + (size_t)i * D_, enc_ln2_b + (size_t)i * D_);
  }

  // ---------------- decoder ----------------
  embed_kernel<<<dim3(BT_), blk, 0, stream>>>(y, dec_emb, dd, db16);
  for (int i = 0; i < L_; ++i) {
    attention(db16, db16, true,
              dec_sa_qkv_w + (size_t)i * 3 * WQKV, dec_sa_qkv_b + (size_t)i * 3 * HD_,
              dec_sa_out_w + (size_t)i * HD_ * D_, dec_sa_out_b + (size_t)i * D_,
              dd, db16, 1, dec_ln1_g + (size_t)i * D_, dec_ln1_b + (size_t)i * D_);
    attention(db16, hb16, false,
              dec_ca_qkv_w + (size_t)i * 3 * WQKV, dec_ca_qkv_b + (size_t)i * 3 * HD_,
              dec_ca_out_w + (size_t)i * HD_ * D_, dec_ca_out_b + (size_t)i * D_,
              dd, db16, 0, dec_ln2_g + (size_t)i * D_, dec_ln2_b + (size_t)i * D_);
    ffn(dd, db16, dec_ff_w1 + (size_t)i * D_ * F_, dec_ff_b1 + (size_t)i * F_,
        dec_ff_w2 + (size_t)i * F_ * D_, dec_ff_b2 + (size_t)i * D_,
        dec_ln3_g + (size_t)i * D_, dec_ln3_b + (size_t)i * D_);
  }

  // ---------------- LM head -> f32 logits ----------------
  gemm(false, true, false, 0, 0, db16, D_, 0, 0, head_w, V_, 0, 0,
       out, V_, 0, 0, 0, nullptr, -1,
       BT_, V_, D_, 1, 1, 1, 1.0f, head_b, 0);
}

// Round 12
// 2349.843 us; speedup vs baseline: 1.2143x; 1.2143x over previous
//
#include <hip/hip_runtime.h>
#include <hip/hip_bf16.h>

#define B_ 2
#define T_ 512
#define D_ 512
#define H_ 8
#define L_ 6
#define F_ 2048
#define V_ 32000
#define BT_ (B_ * T_)
#define HD_ (H_ * D_)
#define BH_ (B_ * H_)

typedef __attribute__((ext_vector_type(8))) short short8;
typedef __attribute__((ext_vector_type(4))) short short4v;
typedef __attribute__((ext_vector_type(4))) float f32x4;

__device__ __forceinline__ short f2b(float f) {
  __hip_bfloat16 h = __float2bfloat16(f);
  short u; __builtin_memcpy(&u, &h, 2); return u;
}
__device__ __forceinline__ void store_c(float* p, float v) { *p = v; }
__device__ __forceinline__ void store_c(short* p, float v) { *p = f2b(v); }

// ---------------- embedding * sqrt(D) + sinusoidal PE (f32 + bf16 copies) ----------------
__global__ __launch_bounds__(256) void embed_kernel(
    const int* __restrict__ tok, const float* __restrict__ emb,
    float* __restrict__ out, short* __restrict__ out16)
{
  const int row = blockIdx.x;            // b*T + t
  const int t = row & (T_ - 1);
  const int token = tok[row];
  const float* e = emb + (size_t)token * D_;
  float* o = out + (size_t)row * D_;
  short* o16 = out16 + (size_t)row * D_;
  const float scale = sqrtf((float)D_);
  const float nl = -logf(10000.0f);
  for (int d = threadIdx.x; d < D_; d += 256) {
    int i = d >> 1;
    float wl = expf(nl * (2.0f * (float)i) / (float)D_);
    float ang = (float)t * wl;
    float pe = (d & 1) ? cosf(ang) : sinf(ang);
    float v = e[d] * scale + pe;
    o[d] = v; o16[d] = f2b(v);
  }
}

// ---------------- generic MFMA GEMM (r6 structure: single-buffer + reg prefetch) --------
// A: bf16 [.,K] k-contig. B: BTM ? bf16 [N][K] k-contig : f32 [K][N].
// BM in {64,128}, BN=128. z = batch(nh) x ksplit.
// a_once: A offset = (hh>=1 ? a_lo : 0)  (cross-attn QKV) instead of hh*a_lo.
// cskip: skip blocks with bn > bm+BM-1 (causal upper triangle of S).
// cklim: limit K-steps to (bm>>6)+1 (causal PV: P[q][k]=0 for k>q).
// trans_hh: transposed bf16 store for that sub-batch; relu: fused epilogue relu.
template<bool BTM, typename OutT, int BM>
__global__ __launch_bounds__(256, 3) void mfma_gemm(
    const short* __restrict__ A, long lda, long a_hi, long a_lo, int a_once,
    const void* __restrict__ Bv, long ldb, long b_hi, long b_lo,
    OutT* __restrict__ C, long ldc, long c_hi, long c_lo, long pstride,
    short* __restrict__ Ct, int trans_hh, int relu, int cskip, int cklim,
    int K, int nh, int ksplit, float scale,
    const float* __restrict__ bias, long bias_stride)
{
  constexpr int SA = BM + 1;
  constexpr int AU = BM / 32;
  constexpr int WRN = (BM == 128) ? 2 : 1;
  constexpr int WN  = (BM == 128) ? 64 : 32;
  constexpr int NR  = WN / 16;
  __shared__ short8 As8[8 * SA];
  __shared__ short8 Bs8[8 * 129];
  const int tid = threadIdx.x;
  const int bh = blockIdx.z / ksplit;
  const int kz = blockIdx.z - bh * ksplit;
  const int bb = bh / nh, hh = bh - bb * nh;
  const long a_off = a_once ? (hh >= 1 ? a_lo : 0) : (long)hh * a_lo;
  const short* Ab = A + (long)bb * a_hi + a_off;
  const short* Bbs = (const short*)Bv + (long)bb * b_hi + (long)hh * b_lo;
  const float* Bbf = (const float*)Bv + (long)bb * b_hi + (long)hh * b_lo;
  OutT* Cb = C + (long)bb * c_hi + (long)hh * c_lo + (long)kz * pstride;

  const int gx = gridDim.x, gy = gridDim.y;
  const int nwg = gx * gy;
  int lin = blockIdx.y * gx + blockIdx.x;
  {
    const int xcd = lin & 7, idx = lin >> 3;
    const int q = nwg >> 3, r = nwg & 7;
    lin = (xcd < r ? xcd * (q + 1) : r * (q + 1) + (xcd - r) * q) + idx;
  }
  const int bn = (lin / gy) * 128;
  const int bm = (lin % gy) * BM;
  if (cskip && bn > bm + BM - 1) return;   // causal upper triangle: S never read

  const int klen = K / ksplit, kbase = kz * klen;
  const int lane = tid & 63, wid = tid >> 6;
  const int wr = (WRN == 2) ? (wid >> 1) : 0;
  const int wc = (WRN == 2) ? (wid & 1) : wid;
  const int lg = lane >> 4, r16 = lane & 15;

  int arow[AU], acol[AU];
#pragma unroll
  for (int u = 0; u < AU; ++u) { int o = u * 256 + tid; arow[u] = o >> 3; acol[u] = o & 7; }
  int brow[4], bcol[4];
#pragma unroll
  for (int u = 0; u < 4; ++u) { int o = u * 256 + tid; brow[u] = o >> 3; bcol[u] = o & 7; }
  const int ncol = tid & 127, nsh = tid >> 7;

  short8 pa[AU];
  short8 pbt[4];
  float  pbn[4][8];

  auto load = [&](int k0) {
#pragma unroll
    for (int u = 0; u < AU; ++u)
      pa[u] = *(const short8*)(Ab + (long)(bm + arow[u]) * lda + (k0 + acol[u] * 8));
    if constexpr (BTM) {
#pragma unroll
      for (int u = 0; u < 4; ++u)
        pbt[u] = *(const short8*)(Bbs + (long)(bn + brow[u]) * ldb + (k0 + bcol[u] * 8));
    } else {
      const float* s = Bbf + (long)(k0 + nsh * 32) * ldb + (bn + ncol);
#pragma unroll
      for (int i = 0; i < 4; ++i)
#pragma unroll
        for (int j = 0; j < 8; ++j)
          pbn[i][j] = s[(long)(i * 8 + j) * ldb];
    }
  };
  auto stage = [&]() {
#pragma unroll
    for (int u = 0; u < AU; ++u) As8[acol[u] * SA + arow[u]] = pa[u];
    if constexpr (BTM) {
#pragma unroll
      for (int u = 0; u < 4; ++u) Bs8[bcol[u] * 129 + brow[u]] = pbt[u];
    } else {
#pragma unroll
      for (int i = 0; i < 4; ++i) {
        short8 v;
#pragma unroll
        for (int j = 0; j < 8; ++j) v[j] = f2b(pbn[i][j]);
        Bs8[(nsh * 4 + i) * 129 + ncol] = v;
      }
    }
  };

  f32x4 acc[4][NR] = {};
  auto domfma = [&]() {
#pragma unroll
    for (int kb = 0; kb < 2; ++kb) {
      const int cha = (kb * 4 + lg) * SA;
      const int chb = (kb * 4 + lg) * 129;
      short8 a0 = As8[cha + wr * 64 +  0 + r16];
      short8 a1 = As8[cha + wr * 64 + 16 + r16];
      short8 a2 = As8[cha + wr * 64 + 32 + r16];
      short8 a3 = As8[cha + wr * 64 + 48 + r16];
#pragma unroll
      for (int n = 0; n < NR; ++n) {
        short8 bfr = Bs8[chb + wc * WN + n * 16 + r16];
        acc[0][n] = __builtin_amdgcn_mfma_f32_16x16x32_bf16(a0, bfr, acc[0][n], 0, 0, 0);
        acc[1][n] = __builtin_amdgcn_mfma_f32_16x16x32_bf16(a1, bfr, acc[1][n], 0, 0, 0);
        acc[2][n] = __builtin_amdgcn_mfma_f32_16x16x32_bf16(a2, bfr, acc[2][n], 0, 0, 0);
        acc[3][n] = __builtin_amdgcn_mfma_f32_16x16x32_bf16(a3, bfr, acc[3][n], 0, 0, 0);
      }
    }
  };

  int nsteps = klen >> 6;
  if (cklim) { const int lim = (bm >> 6) + 1; if (lim < nsteps) nsteps = lim; }
  load(kbase);
  stage();
  __syncthreads();
  for (int t = 0; t < nsteps; ++t) {
    const bool more = (t + 1 < nsteps);
    if (more) load(kbase + (t + 1) * 64);
    domfma();
    if (more) { __syncthreads(); stage(); __syncthreads(); }
  }

  const float* bp = bias ? bias + (long)hh * bias_stride : nullptr;
  if (hh == trans_hh) {
#pragma unroll
    for (int m = 0; m < 4; ++m)
#pragma unroll
      for (int n = 0; n < NR; ++n) {
        const int col = bn + wc * WN + n * 16 + r16;
        const float badd = bp ? bp[col] : 0.0f;
        short4v sv;
#pragma unroll
        for (int rr = 0; rr < 4; ++rr) sv[rr] = f2b(acc[m][n][rr] * scale + badd);
        *(short4v*)(Ct + (long)col * BT_ + (bm + wr * 64 + m * 16 + lg * 4)) = sv;
      }
  } else {
#pragma unroll
    for (int m = 0; m < 4; ++m)
#pragma unroll
      for (int rr = 0; rr < 4; ++rr) {
        const int row = bm + wr * 64 + m * 16 + lg * 4 + rr;
        OutT* crow = Cb + (long)row * ldc + bn + wc * WN + r16;
#pragma unroll
        for (int n = 0; n < NR; ++n) {
          float v = acc[m][n][rr] * scale;
          if (bp) v += bp[bn + wc * WN + n * 16 + r16];
          if (relu) v = fmaxf(v, 0.0f);
          store_c(&crow[n * 16], v);
        }
      }
  }
}

// ---- fused: x = resid + bias + sum_z partial; resid(f32) = LN(x)*g+b; + bf16 copy ----
__global__ __launch_bounds__(256) void reduce_ln_kernel(
    const float* __restrict__ P, long pstride, int ks,
    const float* __restrict__ bias, float* __restrict__ hbuf, short* __restrict__ h16,
    const float* __restrict__ gam, const float* __restrict__ bet)
{
  __shared__ float red[256];
  const int row = blockIdx.x, tid = threadIdx.x;
  const long base = (long)row * D_;
  float s0 = hbuf[base + tid] + bias[tid];
  float s1 = hbuf[base + tid + 256] + bias[tid + 256];
  for (int z = 0; z < ks; ++z) {
    s0 += P[(long)z * pstride + base + tid];
    s1 += P[(long)z * pstride + base + tid + 256];
  }
  red[tid] = s0 + s1; __syncthreads();
  for (int o = 128; o > 0; o >>= 1) { if (tid < o) red[tid] += red[tid + o]; __syncthreads(); }
  const float mean = red[0] * (1.0f / D_); __syncthreads();
  const float d0 = s0 - mean, d1 = s1 - mean;
  red[tid] = d0 * d0 + d1 * d1; __syncthreads();
  for (int o = 128; o > 0; o >>= 1) { if (tid < o) red[tid] += red[tid + o]; __syncthreads(); }
  const float inv = rsqrtf(red[0] * (1.0f / D_) + 1e-6f);
  const float v0 = d0 * inv * gam[tid] + bet[tid];
  const float v1 = d1 * inv * gam[tid + 256] + bet[tid + 256];
  hbuf[base + tid] = v0;       h16[base + tid] = f2b(v0);
  hbuf[base + tid + 256] = v1; h16[base + tid + 256] = f2b(v1);
}

// ------- single-pass row softmax (f32 in, bf16 out); causal k<=q; tail -> 0 -------
__global__ __launch_bounds__(256) void softmax_kernel(
    const float* __restrict__ S, short* __restrict__ P, int causal)
{
  __shared__ float red[256];
  const int q = blockIdx.x, bh = blockIdx.y, tid = threadIdx.x;
  const float* row = S + ((size_t)bh * T_ + q) * T_;
  short* prow = P + ((size_t)bh * T_ + q) * T_;
  const int n = causal ? (q + 1) : T_;
  const float v0 = row[tid], v1 = row[tid + 256];
  const bool in0 = tid < n, in1 = (tid + 256) < n;
  red[tid] = fmaxf(in0 ? v0 : -3.0e38f, in1 ? v1 : -3.0e38f);
  __syncthreads();
  for (int o = 128; o > 0; o >>= 1) { if (tid < o) red[tid] = fmaxf(red[tid], red[tid + o]); __syncthreads(); }
  const float m = red[0]; __syncthreads();
  const float e0 = in0 ? expf(v0 - m) : 0.0f;
  const float e1 = in1 ? expf(v1 - m) : 0.0f;
  red[tid] = e0 + e1; __syncthreads();
  for (int o = 128; o > 0; o >>= 1) { if (tid < o) red[tid] += red[tid + o]; __syncthreads(); }
  const float inv = 1.0f / red[0];
  prow[tid] = f2b(e0 * inv);
  prow[tid + 256] = f2b(e1 * inv);
}

extern "C" void kernel_launch(void* const* d_in, const int* in_sizes, int n_in,
                              void* d_out, int out_size, void* d_ws, size_t ws_size,
                              hipStream_t stream)
{
  const int*   x         = (const int*)d_in[0];
  const int*   y         = (const int*)d_in[1];
  const float* enc_emb   = (const float*)d_in[2];
  const float* dec_emb   = (const float*)d_in[3];
  const float* enc_qkv_w = (const float*)d_in[4];
  const float* enc_qkv_b = (const float*)d_in[5];
  const float* enc_out_w = (const float*)d_in[6];
  const float* enc_out_b = (const float*)d_in[7];
  const float* enc_ln1_g = (const float*)d_in[8];
  const float* enc_ln1_b = (const float*)d_in[9];
  const float* enc_ff_w1 = (const float*)d_in[10];
  const float* enc_ff_b1 = (const float*)d_in[11];
  const float* enc_ff_w2 = (const float*)d_in[12];
  const float* enc_ff_b2 = (const float*)d_in[13];
  const float* enc_ln2_g = (const float*)d_in[14];
  const float* enc_ln2_b = (const float*)d_in[15];
  const float* dec_sa_qkv_w = (const float*)d_in[16];
  const float* dec_sa_qkv_b = (const float*)d_in[17];
  const float* dec_sa_out_w = (const float*)d_in[18];
  const float* dec_sa_out_b = (const float*)d_in[19];
  const float* dec_ln1_g = (const float*)d_in[20];
  const float* dec_ln1_b = (const float*)d_in[21];
  const float* dec_ca_qkv_w = (const float*)d_in[22];
  const float* dec_ca_qkv_b = (const float*)d_in[23];
  const float* dec_ca_out_w = (const float*)d_in[24];
  const float* dec_ca_out_b = (const float*)d_in[25];
  const float* dec_ln2_g = (const float*)d_in[26];
  const float* dec_ln2_b = (const float*)d_in[27];
  const float* dec_ff_w1 = (const float*)d_in[28];
  const float* dec_ff_b1 = (const float*)d_in[29];
  const float* dec_ff_w2 = (const float*)d_in[30];
  const float* dec_ff_b2 = (const float*)d_in[31];
  const float* dec_ln3_g = (const float*)d_in[32];
  const float* dec_ln3_b = (const float*)d_in[33];
  const float* head_w    = (const float*)d_in[34];
  const float* head_b    = (const float*)d_in[35];
  float* out = (float*)d_out;

  // ---- workspace carve-up ----
  char* wsb = (char*)d_ws;
  size_t off = 0;
  auto carve = [&](size_t bytes) { char* p = wsb + off; off += (bytes + 255) & ~255ull; return p; };
  float* h    = (float*)carve((size_t)BT_ * D_ * 4);
  float* dd   = (float*)carve((size_t)BT_ * D_ * 4);
  short* hb16 = (short*)carve((size_t)BT_ * D_ * 2);
  short* db16 = (short*)carve((size_t)BT_ * D_ * 2);
  short* Qb   = (short*)carve((size_t)BT_ * HD_ * 2);
  short* Kb   = (short*)carve((size_t)BT_ * HD_ * 2);
  short* Vt   = (short*)carve((size_t)HD_ * BT_ * 2);
  float* Sb   = (float*)carve((size_t)BH_ * T_ * T_ * 4);  // S + split-K partials
  short* Pb   = (short*)carve((size_t)BH_ * T_ * T_ * 2);
  short* Ob   = Qb;   // Q dead after QK^T
  short* mid  = Qb;   // attn buffers dead during FFN
  (void)ws_size;

  dim3 blk(256);
  const long TT  = (long)T_ * T_;
  const long THD = (long)T_ * HD_;
  const long WQKV = (long)D_ * HD_;

  auto gemm = [&](bool bt, bool of32, bool bm64, int relu, int cskip, int cklim,
                  const short* A, long lda, long a_hi, long a_lo, int a_once,
                  const void* Bp, long ldb, long b_hi, long b_lo,
                  void* Cp, long ldc, long c_hi, long c_lo, long pstride,
                  short* Ct, int trans_hh,
                  int M, int N, int K, int batch, int nh, int ksplit,
                  float scale, const float* bias, long bstride) {
    dim3 grd(N / 128, M / (bm64 ? 64 : 128), batch * ksplit);
    if (bm64) {
      if (bt) {
        if (of32) mfma_gemm<true , float, 64><<<grd, blk, 0, stream>>>(A, lda, a_hi, a_lo, a_once, Bp, ldb, b_hi, b_lo,
            (float*)Cp, ldc, c_hi, c_lo, pstride, Ct, trans_hh, relu, cskip, cklim, K, nh, ksplit, scale, bias, bstride);
        else      mfma_gemm<true , short, 64><<<grd, blk, 0, stream>>>(A, lda, a_hi, a_lo, a_once, Bp, ldb, b_hi, b_lo,
            (short*)Cp, ldc, c_hi, c_lo, pstride, Ct, trans_hh, relu, cskip, cklim, K, nh, ksplit, scale, bias, bstride);
      } else {
        if (of32) mfma_gemm<false, float, 64><<<grd, blk, 0, stream>>>(A, lda, a_hi, a_lo, a_once, Bp, ldb, b_hi, b_lo,
            (float*)Cp, ldc, c_hi, c_lo, pstride, Ct, trans_hh, relu, cskip, cklim, K, nh, ksplit, scale, bias, bstride);
        else      mfma_gemm<false, short, 64><<<grd, blk, 0, stream>>>(A, lda, a_hi, a_lo, a_once, Bp, ldb, b_hi, b_lo,
            (short*)Cp, ldc, c_hi, c_lo, pstride, Ct, trans_hh, relu, cskip, cklim, K, nh, ksplit, scale, bias, bstride);
      }
    } else {
      if (of32) mfma_gemm<false, float, 128><<<grd, blk, 0, stream>>>(A, lda, a_hi, a_lo, a_once, Bp, ldb, b_hi, b_lo,
          (float*)Cp, ldc, c_hi, c_lo, pstride, Ct, trans_hh, relu, cskip, cklim, K, nh, ksplit, scale, bias, bstride);
      else      mfma_gemm<false, short, 128><<<grd, blk, 0, stream>>>(A, lda, a_hi, a_lo, a_once, Bp, ldb, b_hi, b_lo,
          (short*)Cp, ldc, c_hi, c_lo, pstride, Ct, trans_hh, relu, cskip, cklim, K, nh, ksplit, scale, bias, bstride);
    }
  };

  auto attention = [&](const short* qsrc, const short* kvsrc, bool self,
                       const float* qkvw, const float* qkvb,
                       const float* ow, const float* ob,
                       float* resid, short* resid16, int causal,
                       const float* lng, const float* lnb) {
    // fused Q,K,V (z=3); hh=0->Qb (from qsrc), hh=1->Kb, hh=2->transposed Vt
    // (K,V read kvsrc via a_once step offset; ==qsrc for self)
    gemm(false, false, true, 0, 0, 0, qsrc, D_, 0, (long)(kvsrc - qsrc), 1,
         qkvw, HD_, 0, WQKV,
         Qb, HD_, 0, (long)(Kb - Qb), 0, Vt, 2,
         BT_, HD_, D_, 3, 3, 1, 1.0f, qkvb, HD_);
    // S = Q K^T / sqrt(D); causal skips upper-triangle blocks
    gemm(true, true, true, 0, causal, 0, Qb, HD_, THD, D_, 0, Kb, HD_, THD, D_,
         Sb, T_, (long)H_ * TT, TT, 0, nullptr, -1,
         T_, T_, D_, BH_, H_, 1, 0.044194173824159216f, nullptr, 0);
    softmax_kernel<<<dim3(T_, BH_), blk, 0, stream>>>(Sb, Pb, causal);
    // O = P V (B = V^T, k-contig); causal limits K-steps per row-block
    gemm(true, false, true, 0, 0, causal, Pb, T_, (long)H_ * TT, TT, 0,
         Vt, BT_, T_, (long)D_ * BT_,
         Ob, HD_, THD, D_, 0, nullptr, -1,
         T_, D_, T_, BH_, H_, 1, 1.0f, nullptr, 0);
    // out-projection split-K=8 -> f32 partials in Sb; fused reduce+resid+LN
    gemm(false, true, true, 0, 0, 0, Ob, HD_, 0, 0, 0, ow, D_, 0, 0,
         Sb, D_, 0, 0, (long)BT_ * D_, nullptr, -1,
         BT_, D_, HD_, 1, 1, 8, 1.0f, nullptr, 0);
    reduce_ln_kernel<<<dim3(BT_), blk, 0, stream>>>(
        Sb, (long)BT_ * D_, 8, ob, resid, resid16, lng, lnb);
  };

  auto ffn = [&](float* resid, short* resid16,
                 const float* w1, const float* b1,
                 const float* w2, const float* b2,
                 const float* lng, const float* lnb) {
    // FF1: fused bias+relu epilogue -> bf16 mid (BM=64, grid 256, no split-K)
    gemm(false, false, true, 1, 0, 0, resid16, D_, 0, 0, 0, w1, F_, 0, 0,
         mid, F_, 0, 0, 0, nullptr, -1,
         BT_, F_, D_, 1, 1, 1, 1.0f, b1, 0);
    // FF2: split-K=8 -> f32 partials; fused reduce+resid+LN
    gemm(false, true, true, 0, 0, 0, mid, F_, 0, 0, 0, w2, D_, 0, 0,
         Sb, D_, 0, 0, (long)BT_ * D_, nullptr, -1,
         BT_, D_, F_, 1, 1, 8, 1.0f, nullptr, 0);
    reduce_ln_kernel<<<dim3(BT_), blk, 0, stream>>>(
        Sb, (long)BT_ * D_, 8, b2, resid, resid16, lng, lnb);
  };

  // ---------------- encoder ----------------
  embed_kernel<<<dim3(BT_), blk, 0, stream>>>(x, enc_emb, h, hb16);
  for (int i = 0; i < L_; ++i) {
    attention(hb16, hb16, true,
              enc_qkv_w + (size_t)i * 3 * WQKV, enc_qkv_b + (size_t)i * 3 * HD_,
              enc_out_w + (size_t)i * HD_ * D_, enc_out_b + (size_t)i * D_,
              h, hb16, 0, enc_ln1_g + (size_t)i * D_, enc_ln1_b + (size_t)i * D_);
    ffn(h, hb16, enc_ff_w1 + (size_t)i * D_ * F_, enc_ff_b1 + (size_t)i * F_,
        enc_ff_w2 + (size_t)i * F_ * D_, enc_ff_b2 + (size_t)i * D_,
        enc_ln2_g + (size_t)i * D_, enc_ln2_b + (size_t)i * D_);
  }

  // ---------------- decoder ----------------
  embed_kernel<<<dim3(BT_), blk, 0, stream>>>(y, dec_emb, dd, db16);
  for (int i = 0; i < L_; ++i) {
    attention(db16, db16, true,
              dec_sa_qkv_w + (size_t)i * 3 * WQKV, dec_sa_qkv_b + (size_t)i * 3 * HD_,
              dec_sa_out_w + (size_t)i * HD_ * D_, dec_sa_out_b + (size_t)i * D_,
              dd, db16, 1, dec_ln1_g + (size_t)i * D_, dec_ln1_b + (size_t)i * D_);
    attention(db16, hb16, false,
              dec_ca_qkv_w + (size_t)i * 3 * WQKV, dec_ca_qkv_b + (size_t)i * 3 * HD_,
              dec_ca_out_w + (size_t)i * HD_ * D_, dec_ca_out_b + (size_t)i * D_,
              dd, db16, 0, dec_ln2_g + (size_t)i * D_, dec_ln2_b + (size_t)i * D_);
    ffn(dd, db16, dec_ff_w1 + (size_t)i * D_ * F_, dec_ff_b1 + (size_t)i * F_,
        dec_ff_w2 + (size_t)i * F_ * D_, dec_ff_b2 + (size_t)i * D_,
        dec_ln3_g + (size_t)i * D_, dec_ln3_b + (size_t)i * D_);
  }

  // ---------------- LM head -> f32 logits ----------------
  gemm(false, true, false, 0, 0, 0, db16, D_, 0, 0, 0, head_w, V_, 0, 0,
       out, V_, 0, 0, 0, nullptr, -1,
       BT_, V_, D_, 1, 1, 1, 1.0f, head_b, 0);
}

// Round 13
// 2342.799 us; speedup vs baseline: 1.2179x; 1.0030x over previous
//
#include <hip/hip_runtime.h>
#include <hip/hip_bf16.h>

#define B_ 2
#define T_ 512
#define D_ 512
#define H_ 8
#define L_ 6
#define F_ 2048
#define V_ 32000
#define BT_ (B_ * T_)
#define HD_ (H_ * D_)
#define BH_ (B_ * H_)

typedef __attribute__((ext_vector_type(8))) short short8;
typedef __attribute__((ext_vector_type(4))) short short4v;
typedef __attribute__((ext_vector_type(4))) float f32x4;

__device__ __forceinline__ short f2b(float f) {
  __hip_bfloat16 h = __float2bfloat16(f);
  short u; __builtin_memcpy(&u, &h, 2); return u;
}
__device__ __forceinline__ void store_c(float* p, float v) { *p = v; }
__device__ __forceinline__ void store_c(short* p, float v) { *p = f2b(v); }

// ---------------- embedding * sqrt(D) + sinusoidal PE (f32 + bf16 copies) ----------------
__global__ __launch_bounds__(256) void embed_kernel(
    const int* __restrict__ tok, const float* __restrict__ emb,
    float* __restrict__ out, short* __restrict__ out16)
{
  const int row = blockIdx.x;            // b*T + t
  const int t = row & (T_ - 1);
  const int token = tok[row];
  const float* e = emb + (size_t)token * D_;
  float* o = out + (size_t)row * D_;
  short* o16 = out16 + (size_t)row * D_;
  const float scale = sqrtf((float)D_);
  const float nl = -logf(10000.0f);
  for (int d = threadIdx.x; d < D_; d += 256) {
    int i = d >> 1;
    float wl = expf(nl * (2.0f * (float)i) / (float)D_);
    float ang = (float)t * wl;
    float pe = (d & 1) ? cosf(ang) : sinf(ang);
    float v = e[d] * scale + pe;
    o[d] = v; o16[d] = f2b(v);
  }
}

// ------- weight prep: f32 [K][N] -> bf16 [N][K] (tiled transpose, z = matrix idx) -------
__global__ __launch_bounds__(256) void wconv_kernel(
    const float* __restrict__ in, short* __restrict__ outp, int K, int N)
{
  __shared__ float tile[64][65];
  const long mstride = (long)K * N;
  const float* src = in + (long)blockIdx.z * mstride;
  short* dst = outp + (long)blockIdx.z * mstride;
  const int k0 = blockIdx.y * 64, n0 = blockIdx.x * 64;
  const int tid = threadIdx.x;
  const int r = tid >> 6, c = tid & 63;
#pragma unroll
  for (int i = 0; i < 16; ++i)
    tile[r + i * 4][c] = src[(long)(k0 + r + i * 4) * N + n0 + c];
  __syncthreads();
#pragma unroll
  for (int i = 0; i < 16; ++i)
    dst[(long)(n0 + r + i * 4) * K + k0 + c] = f2b(tile[c][r + i * 4]);
}

// ---------------- generic MFMA GEMM (r6 structure: single-buffer + reg prefetch) --------
template<bool BTM, typename OutT, int BM>
__global__ __launch_bounds__(256, 3) void mfma_gemm(
    const short* __restrict__ A, long lda, long a_hi, long a_lo, int a_once,
    const void* __restrict__ Bv, long ldb, long b_hi, long b_lo,
    OutT* __restrict__ C, long ldc, long c_hi, long c_lo, long pstride,
    short* __restrict__ Ct, int trans_hh, int relu, int cskip, int cklim,
    int K, int nh, int ksplit, float scale,
    const float* __restrict__ bias, long bias_stride)
{
  constexpr int SA = BM + 1;
  constexpr int AU = BM / 32;
  constexpr int WRN = (BM == 128) ? 2 : 1;
  constexpr int WN  = (BM == 128) ? 64 : 32;
  constexpr int NR  = WN / 16;
  __shared__ short8 As8[8 * SA];
  __shared__ short8 Bs8[8 * 129];
  const int tid = threadIdx.x;
  const int bh = blockIdx.z / ksplit;
  const int kz = blockIdx.z - bh * ksplit;
  const int bb = bh / nh, hh = bh - bb * nh;
  const long a_off = a_once ? (hh >= 1 ? a_lo : 0) : (long)hh * a_lo;
  const short* Ab = A + (long)bb * a_hi + a_off;
  const short* Bbs = (const short*)Bv + (long)bb * b_hi + (long)hh * b_lo;
  const float* Bbf = (const float*)Bv + (long)bb * b_hi + (long)hh * b_lo;
  OutT* Cb = C + (long)bb * c_hi + (long)hh * c_lo + (long)kz * pstride;

  const int gx = gridDim.x, gy = gridDim.y;
  const int nwg = gx * gy;
  int lin = blockIdx.y * gx + blockIdx.x;
  {
    const int xcd = lin & 7, idx = lin >> 3;
    const int q = nwg >> 3, r = nwg & 7;
    lin = (xcd < r ? xcd * (q + 1) : r * (q + 1) + (xcd - r) * q) + idx;
  }
  const int bn = (lin / gy) * 128;
  const int bm = (lin % gy) * BM;
  if (cskip && bn > bm + BM - 1) return;   // causal upper triangle: S never read

  const int klen = K / ksplit, kbase = kz * klen;
  const int lane = tid & 63, wid = tid >> 6;
  const int wr = (WRN == 2) ? (wid >> 1) : 0;
  const int wc = (WRN == 2) ? (wid & 1) : wid;
  const int lg = lane >> 4, r16 = lane & 15;

  int arow[AU], acol[AU];
#pragma unroll
  for (int u = 0; u < AU; ++u) { int o = u * 256 + tid; arow[u] = o >> 3; acol[u] = o & 7; }
  int brow[4], bcol[4];
#pragma unroll
  for (int u = 0; u < 4; ++u) { int o = u * 256 + tid; brow[u] = o >> 3; bcol[u] = o & 7; }
  const int ncol = tid & 127, nsh = tid >> 7;

  short8 pa[AU];
  short8 pbt[4];
  float  pbn[4][8];

  auto load = [&](int k0) {
#pragma unroll
    for (int u = 0; u < AU; ++u)
      pa[u] = *(const short8*)(Ab + (long)(bm + arow[u]) * lda + (k0 + acol[u] * 8));
    if constexpr (BTM) {
#pragma unroll
      for (int u = 0; u < 4; ++u)
        pbt[u] = *(const short8*)(Bbs + (long)(bn + brow[u]) * ldb + (k0 + bcol[u] * 8));
    } else {
      const float* s = Bbf + (long)(k0 + nsh * 32) * ldb + (bn + ncol);
#pragma unroll
      for (int i = 0; i < 4; ++i)
#pragma unroll
        for (int j = 0; j < 8; ++j)
          pbn[i][j] = s[(long)(i * 8 + j) * ldb];
    }
  };
  auto stage = [&]() {
#pragma unroll
    for (int u = 0; u < AU; ++u) As8[acol[u] * SA + arow[u]] = pa[u];
    if constexpr (BTM) {
#pragma unroll
      for (int u = 0; u < 4; ++u) Bs8[bcol[u] * 129 + brow[u]] = pbt[u];
    } else {
#pragma unroll
      for (int i = 0; i < 4; ++i) {
        short8 v;
#pragma unroll
        for (int j = 0; j < 8; ++j) v[j] = f2b(pbn[i][j]);
        Bs8[(nsh * 4 + i) * 129 + ncol] = v;
      }
    }
  };

  f32x4 acc[4][NR] = {};
  auto domfma = [&]() {
#pragma unroll
    for (int kb = 0; kb < 2; ++kb) {
      const int cha = (kb * 4 + lg) * SA;
      const int chb = (kb * 4 + lg) * 129;
      short8 a0 = As8[cha + wr * 64 +  0 + r16];
      short8 a1 = As8[cha + wr * 64 + 16 + r16];
      short8 a2 = As8[cha + wr * 64 + 32 + r16];
      short8 a3 = As8[cha + wr * 64 + 48 + r16];
#pragma unroll
      for (int n = 0; n < NR; ++n) {
        short8 bfr = Bs8[chb + wc * WN + n * 16 + r16];
        acc[0][n] = __builtin_amdgcn_mfma_f32_16x16x32_bf16(a0, bfr, acc[0][n], 0, 0, 0);
        acc[1][n] = __builtin_amdgcn_mfma_f32_16x16x32_bf16(a1, bfr, acc[1][n], 0, 0, 0);
        acc[2][n] = __builtin_amdgcn_mfma_f32_16x16x32_bf16(a2, bfr, acc[2][n], 0, 0, 0);
        acc[3][n] = __builtin_amdgcn_mfma_f32_16x16x32_bf16(a3, bfr, acc[3][n], 0, 0, 0);
      }
    }
  };

  int nsteps = klen >> 6;
  if (cklim) { const int lim = (bm >> 6) + 1; if (lim < nsteps) nsteps = lim; }
  load(kbase);
  stage();
  __syncthreads();
  for (int t = 0; t < nsteps; ++t) {
    const bool more = (t + 1 < nsteps);
    if (more) load(kbase + (t + 1) * 64);
    domfma();
    if (more) { __syncthreads(); stage(); __syncthreads(); }
  }

  const float* bp = bias ? bias + (long)hh * bias_stride : nullptr;
  if (hh == trans_hh) {
#pragma unroll
    for (int m = 0; m < 4; ++m)
#pragma unroll
      for (int n = 0; n < NR; ++n) {
        const int col = bn + wc * WN + n * 16 + r16;
        const float badd = bp ? bp[col] : 0.0f;
        short4v sv;
#pragma unroll
        for (int rr = 0; rr < 4; ++rr) sv[rr] = f2b(acc[m][n][rr] * scale + badd);
        *(short4v*)(Ct + (long)col * BT_ + (bm + wr * 64 + m * 16 + lg * 4)) = sv;
      }
  } else {
#pragma unroll
    for (int m = 0; m < 4; ++m)
#pragma unroll
      for (int rr = 0; rr < 4; ++rr) {
        const int row = bm + wr * 64 + m * 16 + lg * 4 + rr;
        OutT* crow = Cb + (long)row * ldc + bn + wc * WN + r16;
#pragma unroll
        for (int n = 0; n < NR; ++n) {
          float v = acc[m][n][rr] * scale;
          if (bp) v += bp[bn + wc * WN + n * 16 + r16];
          if (relu) v = fmaxf(v, 0.0f);
          store_c(&crow[n * 16], v);
        }
      }
  }
}

// ---- fused: x = resid + bias + sum_z partial; resid(f32) = LN(x)*g+b; + bf16 copy ----
__global__ __launch_bounds__(256) void reduce_ln_kernel(
    const float* __restrict__ P, long pstride, int ks,
    const float* __restrict__ bias, float* __restrict__ hbuf, short* __restrict__ h16,
    const float* __restrict__ gam, const float* __restrict__ bet)
{
  __shared__ float red[256];
  const int row = blockIdx.x, tid = threadIdx.x;
  const long base = (long)row * D_;
  float s0 = hbuf[base + tid] + bias[tid];
  float s1 = hbuf[base + tid + 256] + bias[tid + 256];
  for (int z = 0; z < ks; ++z) {
    s0 += P[(long)z * pstride + base + tid];
    s1 += P[(long)z * pstride + base + tid + 256];
  }
  red[tid] = s0 + s1; __syncthreads();
  for (int o = 128; o > 0; o >>= 1) { if (tid < o) red[tid] += red[tid + o]; __syncthreads(); }
  const float mean = red[0] * (1.0f / D_); __syncthreads();
  const float d0 = s0 - mean, d1 = s1 - mean;
  red[tid] = d0 * d0 + d1 * d1; __syncthreads();
  for (int o = 128; o > 0; o >>= 1) { if (tid < o) red[tid] += red[tid + o]; __syncthreads(); }
  const float inv = rsqrtf(red[0] * (1.0f / D_) + 1e-6f);
  const float v0 = d0 * inv * gam[tid] + bet[tid];
  const float v1 = d1 * inv * gam[tid + 256] + bet[tid + 256];
  hbuf[base + tid] = v0;       h16[base + tid] = f2b(v0);
  hbuf[base + tid + 256] = v1; h16[base + tid + 256] = f2b(v1);
}

// ------- single-pass row softmax (f32 in, bf16 out); causal k<=q; tail -> 0 -------
__global__ __launch_bounds__(256) void softmax_kernel(
    const float* __restrict__ S, short* __restrict__ P, int causal)
{
  __shared__ float red[256];
  const int q = blockIdx.x, bh = blockIdx.y, tid = threadIdx.x;
  const float* row = S + ((size_t)bh * T_ + q) * T_;
  short* prow = P + ((size_t)bh * T_ + q) * T_;
  const int n = causal ? (q + 1) : T_;
  const float v0 = row[tid], v1 = row[tid + 256];
  const bool in0 = tid < n, in1 = (tid + 256) < n;
  red[tid] = fmaxf(in0 ? v0 : -3.0e38f, in1 ? v1 : -3.0e38f);
  __syncthreads();
  for (int o = 128; o > 0; o >>= 1) { if (tid < o) red[tid] = fmaxf(red[tid], red[tid + o]); __syncthreads(); }
  const float m = red[0]; __syncthreads();
  const float e0 = in0 ? expf(v0 - m) : 0.0f;
  const float e1 = in1 ? expf(v1 - m) : 0.0f;
  red[tid] = e0 + e1; __syncthreads();
  for (int o = 128; o > 0; o >>= 1) { if (tid < o) red[tid] += red[tid + o]; __syncthreads(); }
  const float inv = 1.0f / red[0];
  prow[tid] = f2b(e0 * inv);
  prow[tid + 256] = f2b(e1 * inv);
}

extern "C" void kernel_launch(void* const* d_in, const int* in_sizes, int n_in,
                              void* d_out, int out_size, void* d_ws, size_t ws_size,
                              hipStream_t stream)
{
  const int*   x         = (const int*)d_in[0];
  const int*   y         = (const int*)d_in[1];
  const float* enc_emb   = (const float*)d_in[2];
  const float* dec_emb   = (const float*)d_in[3];
  const float* enc_qkv_w = (const float*)d_in[4];
  const float* enc_qkv_b = (const float*)d_in[5];
  const float* enc_out_w = (const float*)d_in[6];
  const float* enc_out_b = (const float*)d_in[7];
  const float* enc_ln1_g = (const float*)d_in[8];
  const float* enc_ln1_b = (const float*)d_in[9];
  const float* enc_ff_w1 = (const float*)d_in[10];
  const float* enc_ff_b1 = (const float*)d_in[11];
  const float* enc_ff_w2 = (const float*)d_in[12];
  const float* enc_ff_b2 = (const float*)d_in[13];
  const float* enc_ln2_g = (const float*)d_in[14];
  const float* enc_ln2_b = (const float*)d_in[15];
  const float* dec_sa_qkv_w = (const float*)d_in[16];
  const float* dec_sa_qkv_b = (const float*)d_in[17];
  const float* dec_sa_out_w = (const float*)d_in[18];
  const float* dec_sa_out_b = (const float*)d_in[19];
  const float* dec_ln1_g = (const float*)d_in[20];
  const float* dec_ln1_b = (const float*)d_in[21];
  const float* dec_ca_qkv_w = (const float*)d_in[22];
  const float* dec_ca_qkv_b = (const float*)d_in[23];
  const float* dec_ca_out_w = (const float*)d_in[24];
  const float* dec_ca_out_b = (const float*)d_in[25];
  const float* dec_ln2_g = (const float*)d_in[26];
  const float* dec_ln2_b = (const float*)d_in[27];
  const float* dec_ff_w1 = (const float*)d_in[28];
  const float* dec_ff_b1 = (const float*)d_in[29];
  const float* dec_ff_w2 = (const float*)d_in[30];
  const float* dec_ff_b2 = (const float*)d_in[31];
  const float* dec_ln3_g = (const float*)d_in[32];
  const float* dec_ln3_b = (const float*)d_in[33];
  const float* head_w    = (const float*)d_in[34];
  const float* head_b    = (const float*)d_in[35];
  float* out = (float*)d_out;

  // ---- workspace carve-up ----
  char* wsb = (char*)d_ws;
  size_t off = 0;
  auto carve = [&](size_t bytes) { char* p = wsb + off; off += (bytes + 255) & ~255ull; return p; };
  float* h    = (float*)carve((size_t)BT_ * D_ * 4);
  float* dd   = (float*)carve((size_t)BT_ * D_ * 4);
  short* hb16 = (short*)carve((size_t)BT_ * D_ * 2);
  short* db16 = (short*)carve((size_t)BT_ * D_ * 2);
  short* Qb   = (short*)carve((size_t)BT_ * HD_ * 2);
  short* Kb   = (short*)carve((size_t)BT_ * HD_ * 2);
  short* Vt   = (short*)carve((size_t)HD_ * BT_ * 2);
  float* Sb   = (float*)carve((size_t)BH_ * T_ * T_ * 4);  // S + split-K partials
  short* Pb   = (short*)carve((size_t)BH_ * T_ * T_ * 2);
  short* Ob   = Qb;   // Q dead after QK^T
  short* mid  = Qb;   // attn buffers dead during FFN

  // converted-weight region (bf16 [N][K]); enabled only if workspace fits
  const size_t QKVG = (size_t)L_ * 3 * D_ * HD_;      // per qkv group
  const size_t OUTG = (size_t)L_ * HD_ * D_;
  const size_t FFG  = (size_t)L_ * D_ * F_;
  const size_t HEADG = (size_t)D_ * V_;
  const size_t conv_bytes = (3 * QKVG + 3 * OUTG + 2 * FFG + 2 * FFG + HEADG) * 2 + 4096;
  const bool WBT = (ws_size >= off + conv_bytes);
  short *Weq = nullptr, *Wdsq = nullptr, *Wdcq = nullptr;
  short *Weo = nullptr, *Wdso = nullptr, *Wdco = nullptr;
  short *Wef1 = nullptr, *Wef2 = nullptr, *Wdf1 = nullptr, *Wdf2 = nullptr, *Whd = nullptr;
  if (WBT) {
    Weq  = (short*)carve(QKVG * 2);  Wdsq = (short*)carve(QKVG * 2);  Wdcq = (short*)carve(QKVG * 2);
    Weo  = (short*)carve(OUTG * 2);  Wdso = (short*)carve(OUTG * 2);  Wdco = (short*)carve(OUTG * 2);
    Wef1 = (short*)carve(FFG * 2);   Wef2 = (short*)carve(FFG * 2);
    Wdf1 = (short*)carve(FFG * 2);   Wdf2 = (short*)carve(FFG * 2);
    Whd  = (short*)carve(HEADG * 2);
  }

  dim3 blk(256);
  const long TT  = (long)T_ * T_;
  const long THD = (long)T_ * HD_;
  const long WQKV = (long)D_ * HD_;

  if (WBT) {
    wconv_kernel<<<dim3(HD_/64, D_/64, 3 * L_), blk, 0, stream>>>(enc_qkv_w, Weq, D_, HD_);
    wconv_kernel<<<dim3(HD_/64, D_/64, 3 * L_), blk, 0, stream>>>(dec_sa_qkv_w, Wdsq, D_, HD_);
    wconv_kernel<<<dim3(HD_/64, D_/64, 3 * L_), blk, 0, stream>>>(dec_ca_qkv_w, Wdcq, D_, HD_);
    wconv_kernel<<<dim3(D_/64, HD_/64, L_), blk, 0, stream>>>(enc_out_w, Weo, HD_, D_);
    wconv_kernel<<<dim3(D_/64, HD_/64, L_), blk, 0, stream>>>(dec_sa_out_w, Wdso, HD_, D_);
    wconv_kernel<<<dim3(D_/64, HD_/64, L_), blk, 0, stream>>>(dec_ca_out_w, Wdco, HD_, D_);
    wconv_kernel<<<dim3(F_/64, D_/64, L_), blk, 0, stream>>>(enc_ff_w1, Wef1, D_, F_);
    wconv_kernel<<<dim3(D_/64, F_/64, L_), blk, 0, stream>>>(enc_ff_w2, Wef2, F_, D_);
    wconv_kernel<<<dim3(F_/64, D_/64, L_), blk, 0, stream>>>(dec_ff_w1, Wdf1, D_, F_);
    wconv_kernel<<<dim3(D_/64, F_/64, L_), blk, 0, stream>>>(dec_ff_w2, Wdf2, F_, D_);
    wconv_kernel<<<dim3(V_/64, D_/64, 1), blk, 0, stream>>>(head_w, Whd, D_, V_);
  }

  auto gemm = [&](bool bt, bool of32, bool bm64, int relu, int cskip, int cklim,
                  const short* A, long lda, long a_hi, long a_lo, int a_once,
                  const void* Bp, long ldb, long b_hi, long b_lo,
                  void* Cp, long ldc, long c_hi, long c_lo, long pstride,
                  short* Ct, int trans_hh,
                  int M, int N, int K, int batch, int nh, int ksplit,
                  float scale, const float* bias, long bstride) {
    dim3 grd(N / 128, M / (bm64 ? 64 : 128), batch * ksplit);
    if (bm64) {
      if (bt) {
        if (of32) mfma_gemm<true , float, 64><<<grd, blk, 0, stream>>>(A, lda, a_hi, a_lo, a_once, Bp, ldb, b_hi, b_lo,
            (float*)Cp, ldc, c_hi, c_lo, pstride, Ct, trans_hh, relu, cskip, cklim, K, nh, ksplit, scale, bias, bstride);
        else      mfma_gemm<true , short, 64><<<grd, blk, 0, stream>>>(A, lda, a_hi, a_lo, a_once, Bp, ldb, b_hi, b_lo,
            (short*)Cp, ldc, c_hi, c_lo, pstride, Ct, trans_hh, relu, cskip, cklim, K, nh, ksplit, scale, bias, bstride);
      } else {
        if (of32) mfma_gemm<false, float, 64><<<grd, blk, 0, stream>>>(A, lda, a_hi, a_lo, a_once, Bp, ldb, b_hi, b_lo,
            (float*)Cp, ldc, c_hi, c_lo, pstride, Ct, trans_hh, relu, cskip, cklim, K, nh, ksplit, scale, bias, bstride);
        else      mfma_gemm<false, short, 64><<<grd, blk, 0, stream>>>(A, lda, a_hi, a_lo, a_once, Bp, ldb, b_hi, b_lo,
            (short*)Cp, ldc, c_hi, c_lo, pstride, Ct, trans_hh, relu, cskip, cklim, K, nh, ksplit, scale, bias, bstride);
      }
    } else {
      if (bt) {
        if (of32) mfma_gemm<true , float, 128><<<grd, blk, 0, stream>>>(A, lda, a_hi, a_lo, a_once, Bp, ldb, b_hi, b_lo,
            (float*)Cp, ldc, c_hi, c_lo, pstride, Ct, trans_hh, relu, cskip, cklim, K, nh, ksplit, scale, bias, bstride);
        else      mfma_gemm<true , short, 128><<<grd, blk, 0, stream>>>(A, lda, a_hi, a_lo, a_once, Bp, ldb, b_hi, b_lo,
            (short*)Cp, ldc, c_hi, c_lo, pstride, Ct, trans_hh, relu, cskip, cklim, K, nh, ksplit, scale, bias, bstride);
      } else {
        if (of32) mfma_gemm<false, float, 128><<<grd, blk, 0, stream>>>(A, lda, a_hi, a_lo, a_once, Bp, ldb, b_hi, b_lo,
            (float*)Cp, ldc, c_hi, c_lo, pstride, Ct, trans_hh, relu, cskip, cklim, K, nh, ksplit, scale, bias, bstride);
        else      mfma_gemm<false, short, 128><<<grd, blk, 0, stream>>>(A, lda, a_hi, a_lo, a_once, Bp, ldb, b_hi, b_lo,
            (short*)Cp, ldc, c_hi, c_lo, pstride, Ct, trans_hh, relu, cskip, cklim, K, nh, ksplit, scale, bias, bstride);
      }
    }
  };

  const int KS = 4;   // split-K for out-proj / FF2 (grid stays 256)

  auto attention = [&](const short* qsrc, const short* kvsrc,
                       const float* qkvw, const short* qkvw16, const float* qkvb,
                       const float* ow, const short* ow16, const float* ob,
                       float* resid, short* resid16, int causal,
                       const float* lng, const float* lnb) {
    // fused Q,K,V (z=3); hh=0->Qb (qsrc), hh=1->Kb, hh=2->transposed Vt
    if (WBT)
      gemm(true, false, true, 0, 0, 0, qsrc, D_, 0, (long)(kvsrc - qsrc), 1,
           qkvw16, D_, 0, WQKV,
           Qb, HD_, 0, (long)(Kb - Qb), 0, Vt, 2,
           BT_, HD_, D_, 3, 3, 1, 1.0f, qkvb, HD_);
    else
      gemm(false, false, true, 0, 0, 0, qsrc, D_, 0, (long)(kvsrc - qsrc), 1,
           qkvw, HD_, 0, WQKV,
           Qb, HD_, 0, (long)(Kb - Qb), 0, Vt, 2,
           BT_, HD_, D_, 3, 3, 1, 1.0f, qkvb, HD_);
    // S = Q K^T / sqrt(D); causal skips upper-triangle blocks
    gemm(true, true, true, 0, causal, 0, Qb, HD_, THD, D_, 0, Kb, HD_, THD, D_,
         Sb, T_, (long)H_ * TT, TT, 0, nullptr, -1,
         T_, T_, D_, BH_, H_, 1, 0.044194173824159216f, nullptr, 0);
    softmax_kernel<<<dim3(T_, BH_), blk, 0, stream>>>(Sb, Pb, causal);
    // O = P V (B = V^T); causal limits K-steps per row-block
    gemm(true, false, true, 0, 0, causal, Pb, T_, (long)H_ * TT, TT, 0,
         Vt, BT_, T_, (long)D_ * BT_,
         Ob, HD_, THD, D_, 0, nullptr, -1,
         T_, D_, T_, BH_, H_, 1, 1.0f, nullptr, 0);
    // out-projection split-K -> f32 partials in Sb; fused reduce+resid+LN
    if (WBT)
      gemm(true, true, true, 0, 0, 0, Ob, HD_, 0, 0, 0, ow16, HD_, 0, 0,
           Sb, D_, 0, 0, (long)BT_ * D_, nullptr, -1,
           BT_, D_, HD_, 1, 1, KS, 1.0f, nullptr, 0);
    else
      gemm(false, true, true, 0, 0, 0, Ob, HD_, 0, 0, 0, ow, D_, 0, 0,
           Sb, D_, 0, 0, (long)BT_ * D_, nullptr, -1,
           BT_, D_, HD_, 1, 1, KS, 1.0f, nullptr, 0);
    reduce_ln_kernel<<<dim3(BT_), blk, 0, stream>>>(
        Sb, (long)BT_ * D_, KS, ob, resid, resid16, lng, lnb);
  };

  auto ffn = [&](float* resid, short* resid16,
                 const float* w1, const short* w116, const float* b1,
                 const float* w2, const short* w216, const float* b2,
                 const float* lng, const float* lnb) {
    // FF1: fused bias+relu epilogue -> bf16 mid (BM=64, grid 256, no split-K)
    if (WBT)
      gemm(true, false, true, 1, 0, 0, resid16, D_, 0, 0, 0, w116, D_, 0, 0,
           mid, F_, 0, 0, 0, nullptr, -1,
           BT_, F_, D_, 1, 1, 1, 1.0f, b1, 0);
    else
      gemm(false, false, true, 1, 0, 0, resid16, D_, 0, 0, 0, w1, F_, 0, 0,
           mid, F_, 0, 0, 0, nullptr, -1,
           BT_, F_, D_, 1, 1, 1, 1.0f, b1, 0);
    // FF2: split-K -> f32 partials; fused reduce+resid+LN
    if (WBT)
      gemm(true, true, true, 0, 0, 0, mid, F_, 0, 0, 0, w216, F_, 0, 0,
           Sb, D_, 0, 0, (long)BT_ * D_, nullptr, -1,
           BT_, D_, F_, 1, 1, KS, 1.0f, nullptr, 0);
    else
      gemm(false, true, true, 0, 0, 0, mid, F_, 0, 0, 0, w2, D_, 0, 0,
           Sb, D_, 0, 0, (long)BT_ * D_, nullptr, -1,
           BT_, D_, F_, 1, 1, KS, 1.0f, nullptr, 0);
    reduce_ln_kernel<<<dim3(BT_), blk, 0, stream>>>(
        Sb, (long)BT_ * D_, KS, b2, resid, resid16, lng, lnb);
  };

  // ---------------- encoder ----------------
  embed_kernel<<<dim3(BT_), blk, 0, stream>>>(x, enc_emb, h, hb16);
  for (int i = 0; i < L_; ++i) {
    attention(hb16, hb16,
              enc_qkv_w + (size_t)i * 3 * WQKV, WBT ? Weq + (size_t)i * 3 * WQKV : nullptr,
              enc_qkv_b + (size_t)i * 3 * HD_,
              enc_out_w + (size_t)i * HD_ * D_, WBT ? Weo + (size_t)i * HD_ * D_ : nullptr,
              enc_out_b + (size_t)i * D_,
              h, hb16, 0, enc_ln1_g + (size_t)i * D_, enc_ln1_b + (size_t)i * D_);
    ffn(h, hb16,
        enc_ff_w1 + (size_t)i * D_ * F_, WBT ? Wef1 + (size_t)i * D_ * F_ : nullptr,
        enc_ff_b1 + (size_t)i * F_,
        enc_ff_w2 + (size_t)i * F_ * D_, WBT ? Wef2 + (size_t)i * F_ * D_ : nullptr,
        enc_ff_b2 + (size_t)i * D_,
        enc_ln2_g + (size_t)i * D_, enc_ln2_b + (size_t)i * D_);
  }

  // ---------------- decoder ----------------
  embed_kernel<<<dim3(BT_), blk, 0, stream>>>(y, dec_emb, dd, db16);
  for (int i = 0; i < L_; ++i) {
    attention(db16, db16,
              dec_sa_qkv_w + (size_t)i * 3 * WQKV, WBT ? Wdsq + (size_t)i * 3 * WQKV : nullptr,
              dec_sa_qkv_b + (size_t)i * 3 * HD_,
              dec_sa_out_w + (size_t)i * HD_ * D_, WBT ? Wdso + (size_t)i * HD_ * D_ : nullptr,
              dec_sa_out_b + (size_t)i * D_,
              dd, db16, 1, dec_ln1_g + (size_t)i * D_, dec_ln1_b + (size_t)i * D_);
    attention(db16, hb16,
              dec_ca_qkv_w + (size_t)i * 3 * WQKV, WBT ? Wdcq + (size_t)i * 3 * WQKV : nullptr,
              dec_ca_qkv_b + (size_t)i * 3 * HD_,
              dec_ca_out_w + (size_t)i * HD_ * D_, WBT ? Wdco + (size_t)i * HD_ * D_ : nullptr,
              dec_ca_out_b + (size_t)i * D_,
              dd, db16, 0, dec_ln2_g + (size_t)i * D_, dec_ln2_b + (size_t)i * D_);
    ffn(dd, db16,
        dec_ff_w1 + (size_t)i * D_ * F_, WBT ? Wdf1 + (size_t)i * D_ * F_ : nullptr,
        dec_ff_b1 + (size_t)i * F_,
        dec_ff_w2 + (size_t)i * F_ * D_, WBT ? Wdf2 + (size_t)i * F_ * D_ : nullptr,
        dec_ff_b2 + (size_t)i * D_,
        dec_ln3_g + (size_t)i * D_, dec_ln3_b + (size_t)i * D_);
  }

  // ---------------- LM head -> f32 logits ----------------
  if (WBT)
    gemm(true, true, false, 0, 0, 0, db16, D_, 0, 0, 0, Whd, D_, 0, 0,
         out, V_, 0, 0, 0, nullptr, -1,
         BT_, V_, D_, 1, 1, 1, 1.0f, head_b, 0);
  else
    gemm(false, true, false, 0, 0, 0, db16, D_, 0, 0, 0, head_w, V_, 0, 0,
         out, V_, 0, 0, 0, nullptr, -1,
         BT_, V_, D_, 1, 1, 1, 1.0f, head_b, 0);
}

// Round 14
// 2259.571 us; speedup vs baseline: 1.2628x; 1.0368x over previous
//
#include <hip/hip_runtime.h>
#include <hip/hip_bf16.h>

#define B_ 2
#define T_ 512
#define D_ 512
#define H_ 8
#define L_ 6
#define F_ 2048
#define V_ 32000
#define BT_ (B_ * T_)
#define HD_ (H_ * D_)
#define BH_ (B_ * H_)

typedef __attribute__((ext_vector_type(8))) short short8;
typedef __attribute__((ext_vector_type(4))) short short4v;
typedef __attribute__((ext_vector_type(4))) float f32x4;

__device__ __forceinline__ short f2b(float f) {
  __hip_bfloat16 h = __float2bfloat16(f);
  short u; __builtin_memcpy(&u, &h, 2); return u;
}
__device__ __forceinline__ void store_c(float* p, float v) { *p = v; }
__device__ __forceinline__ void store_c(short* p, float v) { *p = f2b(v); }

// ------- embedding * sqrt(D) + sinusoidal PE, both streams in one dispatch (y-dim) -------
__global__ __launch_bounds__(256) void embed_kernel(
    const int* __restrict__ tokx, const int* __restrict__ toky,
    const float* __restrict__ emb0, const float* __restrict__ emb1,
    float* __restrict__ out0, float* __restrict__ out1,
    short* __restrict__ o160, short* __restrict__ o161)
{
  const int which = blockIdx.y;
  const int row = blockIdx.x;
  const int t = row & (T_ - 1);
  const int token = which ? toky[row] : tokx[row];
  const float* e = (which ? emb1 : emb0) + (size_t)token * D_;
  float* o = (which ? out1 : out0) + (size_t)row * D_;
  short* o16 = (which ? o161 : o160) + (size_t)row * D_;
  const float scale = sqrtf((float)D_);
  const float nl = -logf(10000.0f);
  for (int d = threadIdx.x; d < D_; d += 256) {
    int i = d >> 1;
    float wl = expf(nl * (2.0f * (float)i) / (float)D_);
    float ang = (float)t * wl;
    float pe = (d & 1) ? cosf(ang) : sinf(ang);
    float v = e[d] * scale + pe;
    o[d] = v; o16[d] = f2b(v);
  }
}

// ------- weight prep: f32 [K][N] -> bf16 [N][K] (tiled transpose, z = matrix idx) -------
__global__ __launch_bounds__(256) void wconv_kernel(
    const float* __restrict__ in, short* __restrict__ outp, int K, int N)
{
  __shared__ float tile[64][65];
  const long mstride = (long)K * N;
  const float* src = in + (long)blockIdx.z * mstride;
  short* dst = outp + (long)blockIdx.z * mstride;
  const int k0 = blockIdx.y * 64, n0 = blockIdx.x * 64;
  const int tid = threadIdx.x;
  const int r = tid >> 6, c = tid & 63;
#pragma unroll
  for (int i = 0; i < 16; ++i)
    tile[r + i * 4][c] = src[(long)(k0 + r + i * 4) * N + n0 + c];
  __syncthreads();
#pragma unroll
  for (int i = 0; i < 16; ++i)
    dst[(long)(n0 + r + i * 4) * K + k0 + c] = f2b(tile[c][r + i * 4]);
}

// ---------------- generic MFMA GEMM (r6 structure: single-buffer + reg prefetch) --------
template<bool BTM, typename OutT, int BM>
__global__ __launch_bounds__(256, BM == 64 ? 4 : 3) void mfma_gemm(
    const short* __restrict__ A, long lda, long a_hi, long a_lo, int a_once,
    const void* __restrict__ Bv, long ldb, long b_hi, long b_lo,
    OutT* __restrict__ C, long ldc, long c_hi, long c_lo, long pstride,
    short* __restrict__ Ct, int trans_hh, int relu, int cskip, int cklim,
    int K, int nh, int ksplit, float scale,
    const float* __restrict__ bias, long bias_stride)
{
  constexpr int SA = BM + 1;
  constexpr int AU = BM / 32;
  constexpr int WRN = (BM == 128) ? 2 : 1;
  constexpr int WN  = (BM == 128) ? 64 : 32;
  constexpr int NR  = WN / 16;
  __shared__ short8 As8[8 * SA];
  __shared__ short8 Bs8[8 * 129];
  const int tid = threadIdx.x;
  const int bh = blockIdx.z / ksplit;
  const int kz = blockIdx.z - bh * ksplit;
  const int bb = bh / nh, hh = bh - bb * nh;
  const long a_off = a_once ? (hh >= 1 ? a_lo : 0) : (long)hh * a_lo;
  const short* Ab = A + (long)bb * a_hi + a_off;
  const short* Bbs = (const short*)Bv + (long)bb * b_hi + (long)hh * b_lo;
  const float* Bbf = (const float*)Bv + (long)bb * b_hi + (long)hh * b_lo;
  OutT* Cb = C + (long)bb * c_hi + (long)hh * c_lo + (long)kz * pstride;

  const int gx = gridDim.x, gy = gridDim.y;
  const int nwg = gx * gy;
  int lin = blockIdx.y * gx + blockIdx.x;
  {
    const int xcd = lin & 7, idx = lin >> 3;
    const int q = nwg >> 3, r = nwg & 7;
    lin = (xcd < r ? xcd * (q + 1) : r * (q + 1) + (xcd - r) * q) + idx;
  }
  const int bn = (lin / gy) * 128;
  const int bm = (lin % gy) * BM;
  if (cskip && bn > bm + BM - 1) return;   // causal upper triangle: S never read

  const int klen = K / ksplit, kbase = kz * klen;
  const int lane = tid & 63, wid = tid >> 6;
  const int wr = (WRN == 2) ? (wid >> 1) : 0;
  const int wc = (WRN == 2) ? (wid & 1) : wid;
  const int lg = lane >> 4, r16 = lane & 15;

  int arow[AU], acol[AU];
#pragma unroll
  for (int u = 0; u < AU; ++u) { int o = u * 256 + tid; arow[u] = o >> 3; acol[u] = o & 7; }
  int brow[4], bcol[4];
#pragma unroll
  for (int u = 0; u < 4; ++u) { int o = u * 256 + tid; brow[u] = o >> 3; bcol[u] = o & 7; }
  const int ncol = tid & 127, nsh = tid >> 7;

  short8 pa[AU];
  short8 pbt[4];
  float  pbn[4][8];

  auto load = [&](int k0) {
#pragma unroll
    for (int u = 0; u < AU; ++u)
      pa[u] = *(const short8*)(Ab + (long)(bm + arow[u]) * lda + (k0 + acol[u] * 8));
    if constexpr (BTM) {
#pragma unroll
      for (int u = 0; u < 4; ++u)
        pbt[u] = *(const short8*)(Bbs + (long)(bn + brow[u]) * ldb + (k0 + bcol[u] * 8));
    } else {
      const float* s = Bbf + (long)(k0 + nsh * 32) * ldb + (bn + ncol);
#pragma unroll
      for (int i = 0; i < 4; ++i)
#pragma unroll
        for (int j = 0; j < 8; ++j)
          pbn[i][j] = s[(long)(i * 8 + j) * ldb];
    }
  };
  auto stage = [&]() {
#pragma unroll
    for (int u = 0; u < AU; ++u) As8[acol[u] * SA + arow[u]] = pa[u];
    if constexpr (BTM) {
#pragma unroll
      for (int u = 0; u < 4; ++u) Bs8[bcol[u] * 129 + brow[u]] = pbt[u];
    } else {
#pragma unroll
      for (int i = 0; i < 4; ++i) {
        short8 v;
#pragma unroll
        for (int j = 0; j < 8; ++j) v[j] = f2b(pbn[i][j]);
        Bs8[(nsh * 4 + i) * 129 + ncol] = v;
      }
    }
  };

  f32x4 acc[4][NR] = {};
  auto domfma = [&]() {
#pragma unroll
    for (int kb = 0; kb < 2; ++kb) {
      const int cha = (kb * 4 + lg) * SA;
      const int chb = (kb * 4 + lg) * 129;
      short8 a0 = As8[cha + wr * 64 +  0 + r16];
      short8 a1 = As8[cha + wr * 64 + 16 + r16];
      short8 a2 = As8[cha + wr * 64 + 32 + r16];
      short8 a3 = As8[cha + wr * 64 + 48 + r16];
#pragma unroll
      for (int n = 0; n < NR; ++n) {
        short8 bfr = Bs8[chb + wc * WN + n * 16 + r16];
        acc[0][n] = __builtin_amdgcn_mfma_f32_16x16x32_bf16(a0, bfr, acc[0][n], 0, 0, 0);
        acc[1][n] = __builtin_amdgcn_mfma_f32_16x16x32_bf16(a1, bfr, acc[1][n], 0, 0, 0);
        acc[2][n] = __builtin_amdgcn_mfma_f32_16x16x32_bf16(a2, bfr, acc[2][n], 0, 0, 0);
        acc[3][n] = __builtin_amdgcn_mfma_f32_16x16x32_bf16(a3, bfr, acc[3][n], 0, 0, 0);
      }
    }
  };

  int nsteps = klen >> 6;
  if (cklim) { const int lim = (bm >> 6) + 1; if (lim < nsteps) nsteps = lim; }
  load(kbase);
  stage();
  __syncthreads();
  for (int t = 0; t < nsteps; ++t) {
    const bool more = (t + 1 < nsteps);
    if (more) load(kbase + (t + 1) * 64);
    domfma();
    if (more) { __syncthreads(); stage(); __syncthreads(); }
  }

  const float* bp = bias ? bias + (long)hh * bias_stride : nullptr;
  if (hh == trans_hh) {
#pragma unroll
    for (int m = 0; m < 4; ++m)
#pragma unroll
      for (int n = 0; n < NR; ++n) {
        const int col = bn + wc * WN + n * 16 + r16;
        const float badd = bp ? bp[col] : 0.0f;
        short4v sv;
#pragma unroll
        for (int rr = 0; rr < 4; ++rr) sv[rr] = f2b(acc[m][n][rr] * scale + badd);
        *(short4v*)(Ct + (long)col * BT_ + (bm + wr * 64 + m * 16 + lg * 4)) = sv;
      }
  } else {
#pragma unroll
    for (int m = 0; m < 4; ++m)
#pragma unroll
      for (int rr = 0; rr < 4; ++rr) {
        const int row = bm + wr * 64 + m * 16 + lg * 4 + rr;
        OutT* crow = Cb + (long)row * ldc + bn + wc * WN + r16;
#pragma unroll
        for (int n = 0; n < NR; ++n) {
          float v = acc[m][n][rr] * scale;
          if (bp) v += bp[bn + wc * WN + n * 16 + r16];
          if (relu) v = fmaxf(v, 0.0f);
          store_c(&crow[n * 16], v);
        }
      }
  }
}

// ---- fused: x = resid + bias + sum_z partial; resid(f32) = LN(x)*g+b; + bf16 copy ----
__global__ __launch_bounds__(256) void reduce_ln_kernel(
    const float* __restrict__ P, long pstride, int ks,
    const float* __restrict__ bias, float* __restrict__ hbuf, short* __restrict__ h16,
    const float* __restrict__ gam, const float* __restrict__ bet)
{
  __shared__ float red[256];
  const int row = blockIdx.x, tid = threadIdx.x;
  const long base = (long)row * D_;
  float s0 = hbuf[base + tid] + bias[tid];
  float s1 = hbuf[base + tid + 256] + bias[tid + 256];
  for (int z = 0; z < ks; ++z) {
    s0 += P[(long)z * pstride + base + tid];
    s1 += P[(long)z * pstride + base + tid + 256];
  }
  red[tid] = s0 + s1; __syncthreads();
  for (int o = 128; o > 0; o >>= 1) { if (tid < o) red[tid] += red[tid + o]; __syncthreads(); }
  const float mean = red[0] * (1.0f / D_); __syncthreads();
  const float d0 = s0 - mean, d1 = s1 - mean;
  red[tid] = d0 * d0 + d1 * d1; __syncthreads();
  for (int o = 128; o > 0; o >>= 1) { if (tid < o) red[tid] += red[tid + o]; __syncthreads(); }
  const float inv = rsqrtf(red[0] * (1.0f / D_) + 1e-6f);
  const float v0 = d0 * inv * gam[tid] + bet[tid];
  const float v1 = d1 * inv * gam[tid + 256] + bet[tid + 256];
  hbuf[base + tid] = v0;       h16[base + tid] = f2b(v0);
  hbuf[base + tid + 256] = v1; h16[base + tid + 256] = f2b(v1);
}

// ------- single-pass row softmax (f32 in, bf16 out); causal k<=q; tail -> 0 -------
__global__ __launch_bounds__(256) void softmax_kernel(
    const float* __restrict__ S, short* __restrict__ P, int causal)
{
  __shared__ float red[256];
  const int q = blockIdx.x, bh = blockIdx.y, tid = threadIdx.x;
  const float* row = S + ((size_t)bh * T_ + q) * T_;
  short* prow = P + ((size_t)bh * T_ + q) * T_;
  const int n = causal ? (q + 1) : T_;
  const float v0 = row[tid], v1 = row[tid + 256];
  const bool in0 = tid < n, in1 = (tid + 256) < n;
  red[tid] = fmaxf(in0 ? v0 : -3.0e38f, in1 ? v1 : -3.0e38f);
  __syncthreads();
  for (int o = 128; o > 0; o >>= 1) { if (tid < o) red[tid] = fmaxf(red[tid], red[tid + o]); __syncthreads(); }
  const float m = red[0]; __syncthreads();
  const float e0 = in0 ? expf(v0 - m) : 0.0f;
  const float e1 = in1 ? expf(v1 - m) : 0.0f;
  red[tid] = e0 + e1; __syncthreads();
  for (int o = 128; o > 0; o >>= 1) { if (tid < o) red[tid] += red[tid + o]; __syncthreads(); }
  const float inv = 1.0f / red[0];
  prow[tid] = f2b(e0 * inv);
  prow[tid + 256] = f2b(e1 * inv);
}

extern "C" void kernel_launch(void* const* d_in, const int* in_sizes, int n_in,
                              void* d_out, int out_size, void* d_ws, size_t ws_size,
                              hipStream_t stream)
{
  const int*   x         = (const int*)d_in[0];
  const int*   y         = (const int*)d_in[1];
  const float* enc_emb   = (const float*)d_in[2];
  const float* dec_emb   = (const float*)d_in[3];
  const float* enc_qkv_w = (const float*)d_in[4];
  const float* enc_qkv_b = (const float*)d_in[5];
  const float* enc_out_w = (const float*)d_in[6];
  const float* enc_out_b = (const float*)d_in[7];
  const float* enc_ln1_g = (const float*)d_in[8];
  const float* enc_ln1_b = (const float*)d_in[9];
  const float* enc_ff_w1 = (const float*)d_in[10];
  const float* enc_ff_b1 = (const float*)d_in[11];
  const float* enc_ff_w2 = (const float*)d_in[12];
  const float* enc_ff_b2 = (const float*)d_in[13];
  const float* enc_ln2_g = (const float*)d_in[14];
  const float* enc_ln2_b = (const float*)d_in[15];
  const float* dec_sa_qkv_w = (const float*)d_in[16];
  const float* dec_sa_qkv_b = (const float*)d_in[17];
  const float* dec_sa_out_w = (const float*)d_in[18];
  const float* dec_sa_out_b = (const float*)d_in[19];
  const float* dec_ln1_g = (const float*)d_in[20];
  const float* dec_ln1_b = (const float*)d_in[21];
  const float* dec_ca_qkv_w = (const float*)d_in[22];
  const float* dec_ca_qkv_b = (const float*)d_in[23];
  const float* dec_ca_out_w = (const float*)d_in[24];
  const float* dec_ca_out_b = (const float*)d_in[25];
  const float* dec_ln2_g = (const float*)d_in[26];
  const float* dec_ln2_b = (const float*)d_in[27];
  const float* dec_ff_w1 = (const float*)d_in[28];
  const float* dec_ff_b1 = (const float*)d_in[29];
  const float* dec_ff_w2 = (const float*)d_in[30];
  const float* dec_ff_b2 = (const float*)d_in[31];
  const float* dec_ln3_g = (const float*)d_in[32];
  const float* dec_ln3_b = (const float*)d_in[33];
  const float* head_w    = (const float*)d_in[34];
  const float* head_b    = (const float*)d_in[35];
  float* out = (float*)d_out;

  // ---- workspace carve-up ----
  char* wsb = (char*)d_ws;
  size_t off = 0;
  auto carve = [&](size_t bytes) { char* p = wsb + off; off += (bytes + 255) & ~255ull; return p; };
  float* h    = (float*)carve((size_t)BT_ * D_ * 4);
  float* dd   = (float*)carve((size_t)BT_ * D_ * 4);
  short* hb16 = (short*)carve((size_t)BT_ * D_ * 2);
  short* db16 = (short*)carve((size_t)BT_ * D_ * 2);
  short* Qb   = (short*)carve((size_t)BT_ * HD_ * 2);
  short* Kb   = (short*)carve((size_t)BT_ * HD_ * 2);
  short* Vt   = (short*)carve((size_t)HD_ * BT_ * 2);
  float* Sb   = (float*)carve((size_t)BH_ * T_ * T_ * 4);  // S + split-K partials
  short* Pb   = (short*)carve((size_t)BH_ * T_ * T_ * 2);
  short* Ob   = Qb;   // Q dead after QK^T
  short* mid  = Qb;   // attn buffers dead during FFN

  // converted-weight region (bf16 [N][K]); enabled only if workspace fits
  const size_t QKVG = (size_t)L_ * 3 * D_ * HD_;
  const size_t OUTG = (size_t)L_ * HD_ * D_;
  const size_t FFG  = (size_t)L_ * D_ * F_;
  const size_t HEADG = (size_t)D_ * V_;
  const size_t conv_bytes = (3 * QKVG + 3 * OUTG + 2 * FFG + 2 * FFG + HEADG) * 2 + 4096;
  const bool WBT = (ws_size >= off + conv_bytes);
  short *Weq = nullptr, *Wdsq = nullptr, *Wdcq = nullptr;
  short *Weo = nullptr, *Wdso = nullptr, *Wdco = nullptr;
  short *Wef1 = nullptr, *Wef2 = nullptr, *Wdf1 = nullptr, *Wdf2 = nullptr, *Whd = nullptr;
  if (WBT) {
    Weq  = (short*)carve(QKVG * 2);  Wdsq = (short*)carve(QKVG * 2);  Wdcq = (short*)carve(QKVG * 2);
    Weo  = (short*)carve(OUTG * 2);  Wdso = (short*)carve(OUTG * 2);  Wdco = (short*)carve(OUTG * 2);
    Wef1 = (short*)carve(FFG * 2);   Wef2 = (short*)carve(FFG * 2);
    Wdf1 = (short*)carve(FFG * 2);   Wdf2 = (short*)carve(FFG * 2);
    Whd  = (short*)carve(HEADG * 2);
  }

  dim3 blk(256);
  const long TT  = (long)T_ * T_;
  const long THD = (long)T_ * HD_;
  const long WQKV = (long)D_ * HD_;

  if (WBT) {
    wconv_kernel<<<dim3(HD_/64, D_/64, 3 * L_), blk, 0, stream>>>(enc_qkv_w, Weq, D_, HD_);
    wconv_kernel<<<dim3(HD_/64, D_/64, 3 * L_), blk, 0, stream>>>(dec_sa_qkv_w, Wdsq, D_, HD_);
    wconv_kernel<<<dim3(HD_/64, D_/64, 3 * L_), blk, 0, stream>>>(dec_ca_qkv_w, Wdcq, D_, HD_);
    wconv_kernel<<<dim3(D_/64, HD_/64, L_), blk, 0, stream>>>(enc_out_w, Weo, HD_, D_);
    wconv_kernel<<<dim3(D_/64, HD_/64, L_), blk, 0, stream>>>(dec_sa_out_w, Wdso, HD_, D_);
    wconv_kernel<<<dim3(D_/64, HD_/64, L_), blk, 0, stream>>>(dec_ca_out_w, Wdco, HD_, D_);
    wconv_kernel<<<dim3(F_/64, D_/64, L_), blk, 0, stream>>>(enc_ff_w1, Wef1, D_, F_);
    wconv_kernel<<<dim3(D_/64, F_/64, L_), blk, 0, stream>>>(enc_ff_w2, Wef2, F_, D_);
    wconv_kernel<<<dim3(F_/64, D_/64, L_), blk, 0, stream>>>(dec_ff_w1, Wdf1, D_, F_);
    wconv_kernel<<<dim3(D_/64, F_/64, L_), blk, 0, stream>>>(dec_ff_w2, Wdf2, F_, D_);
    wconv_kernel<<<dim3(V_/64, D_/64, 1), blk, 0, stream>>>(head_w, Whd, D_, V_);
  }

  auto gemm = [&](bool bt, bool of32, bool bm64, int relu, int cskip, int cklim,
                  const short* A, long lda, long a_hi, long a_lo, int a_once,
                  const void* Bp, long ldb, long b_hi, long b_lo,
                  void* Cp, long ldc, long c_hi, long c_lo, long pstride,
                  short* Ct, int trans_hh,
                  int M, int N, int K, int batch, int nh, int ksplit,
                  float scale, const float* bias, long bstride) {
    dim3 grd(N / 128, M / (bm64 ? 64 : 128), batch * ksplit);
    if (bm64) {
      if (bt) {
        if (of32) mfma_gemm<true , float, 64><<<grd, blk, 0, stream>>>(A, lda, a_hi, a_lo, a_once, Bp, ldb, b_hi, b_lo,
            (float*)Cp, ldc, c_hi, c_lo, pstride, Ct, trans_hh, relu, cskip, cklim, K, nh, ksplit, scale, bias, bstride);
        else      mfma_gemm<true , short, 64><<<grd, blk, 0, stream>>>(A, lda, a_hi, a_lo, a_once, Bp, ldb, b_hi, b_lo,
            (short*)Cp, ldc, c_hi, c_lo, pstride, Ct, trans_hh, relu, cskip, cklim, K, nh, ksplit, scale, bias, bstride);
      } else {
        if (of32) mfma_gemm<false, float, 64><<<grd, blk, 0, stream>>>(A, lda, a_hi, a_lo, a_once, Bp, ldb, b_hi, b_lo,
            (float*)Cp, ldc, c_hi, c_lo, pstride, Ct, trans_hh, relu, cskip, cklim, K, nh, ksplit, scale, bias, bstride);
        else      mfma_gemm<false, short, 64><<<grd, blk, 0, stream>>>(A, lda, a_hi, a_lo, a_once, Bp, ldb, b_hi, b_lo,
            (short*)Cp, ldc, c_hi, c_lo, pstride, Ct, trans_hh, relu, cskip, cklim, K, nh, ksplit, scale, bias, bstride);
      }
    } else {
      if (bt) {
        if (of32) mfma_gemm<true , float, 128><<<grd, blk, 0, stream>>>(A, lda, a_hi, a_lo, a_once, Bp, ldb, b_hi, b_lo,
            (float*)Cp, ldc, c_hi, c_lo, pstride, Ct, trans_hh, relu, cskip, cklim, K, nh, ksplit, scale, bias, bstride);
        else      mfma_gemm<true , short, 128><<<grd, blk, 0, stream>>>(A, lda, a_hi, a_lo, a_once, Bp, ldb, b_hi, b_lo,
            (short*)Cp, ldc, c_hi, c_lo, pstride, Ct, trans_hh, relu, cskip, cklim, K, nh, ksplit, scale, bias, bstride);
      } else {
        if (of32) mfma_gemm<false, float, 128><<<grd, blk, 0, stream>>>(A, lda, a_hi, a_lo, a_once, Bp, ldb, b_hi, b_lo,
            (float*)Cp, ldc, c_hi, c_lo, pstride, Ct, trans_hh, relu, cskip, cklim, K, nh, ksplit, scale, bias, bstride);
        else      mfma_gemm<false, short, 128><<<grd, blk, 0, stream>>>(A, lda, a_hi, a_lo, a_once, Bp, ldb, b_hi, b_lo,
            (short*)Cp, ldc, c_hi, c_lo, pstride, Ct, trans_hh, relu, cskip, cklim, K, nh, ksplit, scale, bias, bstride);
      }
    }
  };

  const int KS = 4;   // split-K for out-proj / FF2

  auto attention = [&](const short* qsrc, const short* kvsrc,
                       const float* qkvw, const short* qkvw16, const float* qkvb,
                       const float* ow, const short* ow16, const float* ob,
                       float* resid, short* resid16, int causal,
                       const float* lng, const float* lnb) {
    // fused Q,K,V (z=3, BM=128 -> 768 blocks); hh=0->Qb, hh=1->Kb, hh=2->Vt^T
    if (WBT)
      gemm(true, false, false, 0, 0, 0, qsrc, D_, 0, (long)(kvsrc - qsrc), 1,
           qkvw16, D_, 0, WQKV,
           Qb, HD_, 0, (long)(Kb - Qb), 0, Vt, 2,
           BT_, HD_, D_, 3, 3, 1, 1.0f, qkvb, HD_);
    else
      gemm(false, false, false, 0, 0, 0, qsrc, D_, 0, (long)(kvsrc - qsrc), 1,
           qkvw, HD_, 0, WQKV,
           Qb, HD_, 0, (long)(Kb - Qb), 0, Vt, 2,
           BT_, HD_, D_, 3, 3, 1, 1.0f, qkvb, HD_);
    // S = Q K^T / sqrt(D); causal skips upper-triangle blocks
    gemm(true, true, true, 0, causal, 0, Qb, HD_, THD, D_, 0, Kb, HD_, THD, D_,
         Sb, T_, (long)H_ * TT, TT, 0, nullptr, -1,
         T_, T_, D_, BH_, H_, 1, 0.044194173824159216f, nullptr, 0);
    softmax_kernel<<<dim3(T_, BH_), blk, 0, stream>>>(Sb, Pb, causal);
    // O = P V (B = V^T); causal limits K-steps per row-block
    gemm(true, false, true, 0, 0, causal, Pb, T_, (long)H_ * TT, TT, 0,
         Vt, BT_, T_, (long)D_ * BT_,
         Ob, HD_, THD, D_, 0, nullptr, -1,
         T_, D_, T_, BH_, H_, 1, 1.0f, nullptr, 0);
    // out-projection split-K -> f32 partials in Sb; fused reduce+resid+LN
    if (WBT)
      gemm(true, true, true, 0, 0, 0, Ob, HD_, 0, 0, 0, ow16, HD_, 0, 0,
           Sb, D_, 0, 0, (long)BT_ * D_, nullptr, -1,
           BT_, D_, HD_, 1, 1, KS, 1.0f, nullptr, 0);
    else
      gemm(false, true, true, 0, 0, 0, Ob, HD_, 0, 0, 0, ow, D_, 0, 0,
           Sb, D_, 0, 0, (long)BT_ * D_, nullptr, -1,
           BT_, D_, HD_, 1, 1, KS, 1.0f, nullptr, 0);
    reduce_ln_kernel<<<dim3(BT_), blk, 0, stream>>>(
        Sb, (long)BT_ * D_, KS, ob, resid, resid16, lng, lnb);
  };

  auto ffn = [&](float* resid, short* resid16,
                 const float* w1, const short* w116, const float* b1,
                 const float* w2, const short* w216, const float* b2,
                 const float* lng, const float* lnb) {
    if (WBT)
      gemm(true, false, true, 1, 0, 0, resid16, D_, 0, 0, 0, w116, D_, 0, 0,
           mid, F_, 0, 0, 0, nullptr, -1,
           BT_, F_, D_, 1, 1, 1, 1.0f, b1, 0);
    else
      gemm(false, false, true, 1, 0, 0, resid16, D_, 0, 0, 0, w1, F_, 0, 0,
           mid, F_, 0, 0, 0, nullptr, -1,
           BT_, F_, D_, 1, 1, 1, 1.0f, b1, 0);
    if (WBT)
      gemm(true, true, true, 0, 0, 0, mid, F_, 0, 0, 0, w216, F_, 0, 0,
           Sb, D_, 0, 0, (long)BT_ * D_, nullptr, -1,
           BT_, D_, F_, 1, 1, KS, 1.0f, nullptr, 0);
    else
      gemm(false, true, true, 0, 0, 0, mid, F_, 0, 0, 0, w2, D_, 0, 0,
           Sb, D_, 0, 0, (long)BT_ * D_, nullptr, -1,
           BT_, D_, F_, 1, 1, KS, 1.0f, nullptr, 0);
    reduce_ln_kernel<<<dim3(BT_), blk, 0, stream>>>(
        Sb, (long)BT_ * D_, KS, b2, resid, resid16, lng, lnb);
  };

  // ---------------- embeddings (both streams, one dispatch) ----------------
  embed_kernel<<<dim3(BT_, 2), blk, 0, stream>>>(x, y, enc_emb, dec_emb, h, dd, hb16, db16);

  // ---------------- encoder ----------------
  for (int i = 0; i < L_; ++i) {
    attention(hb16, hb16,
              enc_qkv_w + (size_t)i * 3 * WQKV, WBT ? Weq + (size_t)i * 3 * WQKV : nullptr,
              enc_qkv_b + (size_t)i * 3 * HD_,
              enc_out_w + (size_t)i * HD_ * D_, WBT ? Weo + (size_t)i * HD_ * D_ : nullptr,
              enc_out_b + (size_t)i * D_,
              h, hb16, 0, enc_ln1_g + (size_t)i * D_, enc_ln1_b + (size_t)i * D_);
    ffn(h, hb16,
        enc_ff_w1 + (size_t)i * D_ * F_, WBT ? Wef1 + (size_t)i * D_ * F_ : nullptr,
        enc_ff_b1 + (size_t)i * F_,
        enc_ff_w2 + (size_t)i * F_ * D_, WBT ? Wef2 + (size_t)i * F_ * D_ : nullptr,
        enc_ff_b2 + (size_t)i * D_,
        enc_ln2_g + (size_t)i * D_, enc_ln2_b + (size_t)i * D_);
  }

  // ---------------- decoder ----------------
  for (int i = 0; i < L_; ++i) {
    attention(db16, db16,
              dec_sa_qkv_w + (size_t)i * 3 * WQKV, WBT ? Wdsq + (size_t)i * 3 * WQKV : nullptr,
              dec_sa_qkv_b + (size_t)i * 3 * HD_,
              dec_sa_out_w + (size_t)i * HD_ * D_, WBT ? Wdso + (size_t)i * HD_ * D_ : nullptr,
              dec_sa_out_b + (size_t)i * D_,
              dd, db16, 1, dec_ln1_g + (size_t)i * D_, dec_ln1_b + (size_t)i * D_);
    attention(db16, hb16,
              dec_ca_qkv_w + (size_t)i * 3 * WQKV, WBT ? Wdcq + (size_t)i * 3 * WQKV : nullptr,
              dec_ca_qkv_b + (size_t)i * 3 * HD_,
              dec_ca_out_w + (size_t)i * HD_ * D_, WBT ? Wdco + (size_t)i * HD_ * D_ : nullptr,
              dec_ca_out_b + (size_t)i * D_,
              dd, db16, 0, dec_ln2_g + (size_t)i * D_, dec_ln2_b + (size_t)i * D_);
    ffn(dd, db16,
        dec_ff_w1 + (size_t)i * D_ * F_, WBT ? Wdf1 + (size_t)i * D_ * F_ : nullptr,
        dec_ff_b1 + (size_t)i * F_,
        dec_ff_w2 + (size_t)i * F_ * D_, WBT ? Wdf2 + (size_t)i * F_ * D_ : nullptr,
        dec_ff_b2 + (size_t)i * D_,
        dec_ln3_g + (size_t)i * D_, dec_ln3_b + (size_t)i * D_);
  }

  // ---------------- LM head -> f32 logits ----------------
  if (WBT)
    gemm(true, true, false, 0, 0, 0, db16, D_, 0, 0, 0, Whd, D_, 0, 0,
         out, V_, 0, 0, 0, nullptr, -1,
         BT_, V_, D_, 1, 1, 1, 1.0f, head_b, 0);
  else
    gemm(false, true, false, 0, 0, 0, db16, D_, 0, 0, 0, head_w, V_, 0, 0,
         out, V_, 0, 0, 0, nullptr, -1,
         BT_, V_, D_, 1, 1, 1, 1.0f, head_b, 0);
}